// Round 7
// baseline (505.259 us; speedup 1.0000x reference)
//
#include <hip/hip_runtime.h>
#include <math.h>

// OctreeAttention: C=256, H=8, HD=32, K=32, G=8, W=40 (pad 48), NW=4096, RPE rows=153
#define SCALE_F 0.17677669529663687f  // 32^-0.5

typedef __bf16 bf16x8 __attribute__((ext_vector_type(8)));
typedef float f32x4 __attribute__((ext_vector_type(4)));

__device__ __forceinline__ unsigned short f2bf(float f) {
  unsigned u = __builtin_bit_cast(unsigned, f);
  u = (u + 0x7FFFu + ((u >> 16) & 1u)) >> 16;
  return (unsigned short)u;
}
__device__ __forceinline__ float bf2f(unsigned short u) {
  return __builtin_bit_cast(float, (unsigned)u << 16);
}
__device__ __forceinline__ unsigned pk2(float a, float b) {
  return (unsigned)f2bf(a) | ((unsigned)f2bf(b) << 16);
}
__device__ __forceinline__ bf16x8 ld16(const void* p) {
  int4 v = *(const int4*)p;
  return __builtin_bit_cast(bf16x8, v);
}
__device__ __forceinline__ void gll16(const void* g, void* l) {
  __builtin_amdgcn_global_load_lds(
      (const __attribute__((address_space(1))) unsigned int*)g,
      (__attribute__((address_space(3))) unsigned int*)l, 16, 0, 0);
}

// =======================================================================
// NEW PATH: 4-kernel split (needs ws_size >= 84.5 MB)
// =======================================================================

// ---- prep: weights -> bf16 ----
// wTq: plain transposed [n=768][k=256] (qkv kernel streams fragments directly).
// pTq: pre-swizzled chunked layout for octa_proj's gll16 staging (unchanged).
__global__ void octa_prep2(const float* __restrict__ qkv_w, const float* __restrict__ proj_w,
                           unsigned short* __restrict__ wTq, unsigned short* __restrict__ pTq)
{
  int e = blockIdx.x * 256 + threadIdx.x;   // 262144
  if (e < 196608) {
    int n = e >> 8, k = e & 255;
    wTq[e] = f2bf(qkv_w[(size_t)k * 768 + n]);
  } else {
    int e2 = e - 196608;
    int kc = e2 >> 13, p2 = e2 & 8191;
    int n = p2 >> 5, cw = p2 & 31;
    int kl = cw ^ (((n >> 1) & 3) << 3);
    pTq[e2] = f2bf(proj_w[(size_t)(kc * 32 + kl) * 256 + n]);
  }
}

// ---- kernel 1: qkv GEMM (M=163840, N=768, K=256) ----
// Block = 32 rows x 768 cols, 8 waves (1Mr x 8Nc), grid 5120.
// A: data rows staged once in LDS (bf16, swizzled), ONE barrier per block.
// B: each lane streams its exact mfma fragment from global (L1/L2-resident).
// K-loop is barrier-free; compiler pipelines loads across the full unroll.
#define KQ_LDS 16384

__global__ __launch_bounds__(512, 4)
void octa_qkv(const float* __restrict__ data, const float* __restrict__ qkv_b,
              const unsigned short* __restrict__ wTq, float* __restrict__ ws,
              char* __restrict__ qg, char* __restrict__ kg, char* __restrict__ vg)
{
  extern __shared__ char smem[];
  const int tid = threadIdx.x, lane = tid & 63, wid = tid >> 6;
  const int ql = lane & 15, lg = lane >> 4;
  const int bm = blockIdx.x;

  // stage A: data rows [bm*32, +32) f32 -> bf16 LDS [32][256], swz ^((row&7)<<4)
  {
    const float4* src = (const float4*)(data + (size_t)bm * 32 * 256);
    #pragma unroll
    for (int rep = 0; rep < 4; ++rep) {
      int f = rep * 512 + tid;          // 2048 float4
      int row = f >> 6, q4 = f & 63;
      float4 d4 = src[f];
      *(uint2*)(smem + row * 512 + ((q4 * 8) ^ ((row & 7) << 4))) =
          make_uint2(pk2(d4.x, d4.y), pk2(d4.z, d4.w));
    }
  }
  __syncthreads();   // the only barrier in this kernel

  // per-lane B row base: col n = wid*96 + nt*16 + ql, k-bytes t*64 + lg*16
  const char* wb = (const char*)wTq + (size_t)(wid * 96 + ql) * 512 + lg * 16;

  f32x4 acc[2][6];
  #pragma unroll
  for (int m = 0; m < 2; ++m)
    #pragma unroll
    for (int n = 0; n < 6; ++n) acc[m][n] = (f32x4){0.f, 0.f, 0.f, 0.f};

  #pragma unroll
  for (int t = 0; t < 8; ++t) {
    bf16x8 bfr[6];
    #pragma unroll
    for (int nt = 0; nt < 6; ++nt)
      bfr[nt] = ld16(wb + nt * 8192 + t * 64);
    bf16x8 af[2];
    #pragma unroll
    for (int mt = 0; mt < 2; ++mt) {
      int row = mt * 16 + ql;
      af[mt] = ld16(smem + row * 512 + ((t * 64 + lg * 16) ^ ((row & 7) << 4)));
    }
    #pragma unroll
    for (int nt = 0; nt < 6; ++nt) {
      acc[0][nt] = __builtin_amdgcn_mfma_f32_16x16x32_bf16(af[0], bfr[nt], acc[0][nt], 0, 0, 0);
      acc[1][nt] = __builtin_amdgcn_mfma_f32_16x16x32_bf16(af[1], bfr[nt], acc[1][nt], 0, 0, 0);
    }
  }

  // epilogue: bias + std partials + scatter to q/k/vT bf16 layouts
  #pragma unroll
  for (int nt = 0; nt < 6; ++nt) {
    int colg = wid * 96 + nt * 16 + ql;
    int tensor = colg >> 8, h = (colg >> 5) & 7, d = colg & 31;
    float bias = qkv_b[colg];
    float s1 = 0.f, s2 = 0.f;
    #pragma unroll
    for (int mt = 0; mt < 2; ++mt) {
      float v4[4];
      #pragma unroll
      for (int r = 0; r < 4; ++r) {
        float v = acc[mt][nt][r] + bias;
        s1 += v; s2 += v * v;
        v4[r] = v;
      }
      int tg0 = bm * 32 + mt * 16 + lg * 4;   // 4-aligned, never crosses a 40-row window
      int w = tg0 / 40, tk0 = tg0 - w * 40;
      size_t slice = (size_t)(w * 8 + h) * 2560;
      if (tensor == 0) {
        #pragma unroll
        for (int r = 0; r < 4; ++r)
          *(unsigned short*)(qg + slice + (tk0 + r) * 64 + d * 2) = f2bf(v4[r] * SCALE_F);
      } else if (tensor == 1) {
        #pragma unroll
        for (int r = 0; r < 4; ++r)
          *(unsigned short*)(kg + slice + (tk0 + r) * 64 + d * 2) = f2bf(v4[r]);
      } else {
        *(uint2*)(vg + slice + d * 80 + tk0 * 2) =
            make_uint2(pk2(v4[0], v4[1]), pk2(v4[2], v4[3]));
      }
    }
    s1 += __shfl_xor(s1, 16); s1 += __shfl_xor(s1, 32);
    s2 += __shfl_xor(s2, 16); s2 += __shfl_xor(s2, 32);
    if (lg == 0) { atomicAdd(ws + colg, s1); atomicAdd(ws + 768 + colg, s2); }
  }
}

// ---- kernel 2: attention, 1 window/block, 8 head-waves, q/k/v direct-from-global ----
#define A2_MSK 0       // mask^T bf16 [40 kj][104 B rows]
#define A2_IDX 4160    // packed idx [32 kj][128 B], XOR bit6 by kj&1
#define A2_RPT 8256    // rpeT f32 [8 h][160]
#define A2_P   13376   // per-wave P [48][80 B] x8 = 30720
#define A2_LDS 44096

__global__ __launch_bounds__(512, 4)
void octa_attn(const char* __restrict__ qg, const char* __restrict__ kg,
               const char* __restrict__ vg, const float* __restrict__ maskp,
               const int* __restrict__ rel_pos, const float* __restrict__ rpe_table,
               char* __restrict__ Og)
{
  extern __shared__ char smem[];
  const int tid = threadIdx.x, w = blockIdx.x, wid = tid >> 6;
  const int lane = tid & 63, ql = lane & 15, lg = lane >> 4, h = wid;
  const int perm = ql * 64 + lg * 16;
  const int vperm = ql * 80 + lg * 16;
  const char* qb = qg + (size_t)(w * 8 + h) * 2560;
  const char* kb = kg + (size_t)(w * 8 + h) * 2560;
  const char* vb = vg + (size_t)(w * 8 + h) * 2560;

  // issue all fragment loads up-front (latency hides under phase-0 staging)
  bf16x8 kf0 = ld16(kb + perm), kf1 = ld16(kb + 1024 + perm), kf2 = ld16(kb + 2048 + perm);
  bf16x8 qf0 = ld16(qb + perm), qf1 = ld16(qb + 1024 + perm), qf2 = ld16(qb + 2048 + perm);
  bf16x8 vA = ld16(vb + vperm);              // d 0..15,  kj 0..31
  bf16x8 vB = ld16(vb + 1280 + vperm);       // d 16..31, kj 0..31
  bf16x8 vC = ld16(vb + 64 + vperm);         // d 0..15,  kj 32..39 (lg=0 only valid)
  bf16x8 vD = ld16(vb + 1280 + 64 + vperm);  // d 16..31, kj 32..39
  if (lg != 0) {      // kj 40..63 don't exist in global: zero them (NaN-safe)
    int4 z = {0, 0, 0, 0};
    vC = __builtin_bit_cast(bf16x8, z);
    vD = __builtin_bit_cast(bf16x8, z);
  }

  // phase 0: stage mask^T, packed idx, transposed rpe
  for (int f = tid; f < 1600; f += 512) {
    float m = maskp[(size_t)w * 1600 + f];
    int qi = f / 40, kj = f - qi * 40;
    *(unsigned short*)(smem + A2_MSK + kj * 104 + qi * 2) = f2bf(m);
  }
  for (int f = tid; f < 1024; f += 512) {
    const int* rp = rel_pos + ((size_t)w * 1024 + f) * 3;
    int c0 = rp[0], c1 = rp[1], c2 = rp[2];
    c0 = min(25, max(-25, c0)); c1 = min(25, max(-25, c1)); c2 = min(25, max(-25, c2));
    unsigned pk = (unsigned)(c0 + 25) | ((unsigned)(c1 + 76) << 10) | ((unsigned)(c2 + 127) << 20);
    int qi8 = f >> 5, kj8 = f & 31;
    *(unsigned*)(smem + A2_IDX + kj8 * 128 + ((qi8 * 4) ^ ((kj8 & 1) << 6))) = pk;
  }
  for (int f = tid; f < 1224; f += 512)
    *(float*)(smem + A2_RPT + (((f & 7) * 160 + (f >> 3)) << 2)) = rpe_table[f];
  __syncthreads();

  // QK^T: ST[kj][qi] = mfma(A=k, B=q)
  f32x4 st[9];
  {
    bf16x8 kf[3] = {kf0, kf1, kf2}, qf[3] = {qf0, qf1, qf2};
    #pragma unroll
    for (int a = 0; a < 3; ++a)
      #pragma unroll
      for (int b = 0; b < 3; ++b)
        st[a * 3 + b] = __builtin_amdgcn_mfma_f32_16x16x32_bf16(
            kf[a], qf[b], (f32x4){0.f, 0.f, 0.f, 0.f}, 0, 0, 0);
  }

  // logits + mask + rpe; per-column (qi) max
  float mx[3] = {-3e38f, -3e38f, -3e38f};
  #pragma unroll
  for (int a = 0; a < 3; ++a) {
    #pragma unroll
    for (int b = 0; b < 3; ++b) {
      #pragma unroll
      for (int r = 0; r < 4; ++r) {
        int kj = a * 16 + lg * 4 + r;
        int qi = b * 16 + ql;
        float s = st[a * 3 + b][r];
        if (kj < 40) {
          if (qi < 40) {
            s += bf2f(*(const unsigned short*)(smem + A2_MSK + kj * 104 + qi * 2));
            if (kj >= 8 && qi >= 8) {
              unsigned pk = *(const unsigned*)(smem + A2_IDX + (kj - 8) * 128 +
                                               (((qi - 8) * 4) ^ (((kj - 8) & 1) << 6)));
              s += *(const float*)(smem + A2_RPT + ((h * 160 + (pk & 1023)) << 2))
                 + *(const float*)(smem + A2_RPT + ((h * 160 + ((pk >> 10) & 1023)) << 2))
                 + *(const float*)(smem + A2_RPT + ((h * 160 + (pk >> 20)) << 2));
            }
          }
        } else {
          s = -1e30f;
        }
        st[a * 3 + b][r] = s;
        mx[b] = fmaxf(mx[b], s);
      }
    }
  }
  #pragma unroll
  for (int b = 0; b < 3; ++b) {
    mx[b] = fmaxf(mx[b], __shfl_xor(mx[b], 16));
    mx[b] = fmaxf(mx[b], __shfl_xor(mx[b], 32));
  }
  float sum[3] = {0.f, 0.f, 0.f};
  #pragma unroll
  for (int a = 0; a < 3; ++a)
    #pragma unroll
    for (int b = 0; b < 3; ++b)
      #pragma unroll
      for (int r = 0; r < 4; ++r) {
        float e = __expf(st[a * 3 + b][r] - mx[b]);
        st[a * 3 + b][r] = e;
        sum[b] += e;
      }
  float inv[3];
  #pragma unroll
  for (int b = 0; b < 3; ++b) {
    sum[b] += __shfl_xor(sum[b], 16);
    sum[b] += __shfl_xor(sum[b], 32);
    inv[b] = 1.f / sum[b];
  }

  // PV in two kj-halves; per-wave P buffer
  char* pb_ = smem + A2_P + wid * 3840;
  f32x4 ot[6];
  #pragma unroll
  for (int i = 0; i < 6; ++i) ot[i] = (f32x4){0.f, 0.f, 0.f, 0.f};

  #pragma unroll
  for (int a = 0; a < 2; ++a)
    #pragma unroll
    for (int b = 0; b < 3; ++b)
      #pragma unroll
      for (int r = 0; r < 4; ++r) {
        int kj = a * 16 + lg * 4 + r, qi = b * 16 + ql;
        *(unsigned short*)(pb_ + qi * 80 + kj * 2) = f2bf(st[a * 3 + b][r] * inv[b]);
      }
  asm volatile("" ::: "memory");
  #pragma unroll
  for (int b = 0; b < 3; ++b) {
    bf16x8 pf = ld16(pb_ + (b * 16 + ql) * 80 + lg * 16);
    ot[b]     = __builtin_amdgcn_mfma_f32_16x16x32_bf16(vA, pf, ot[b], 0, 0, 0);
    ot[3 + b] = __builtin_amdgcn_mfma_f32_16x16x32_bf16(vB, pf, ot[3 + b], 0, 0, 0);
  }
  asm volatile("" ::: "memory");
  #pragma unroll
  for (int b = 0; b < 3; ++b) {
    int qi = b * 16 + ql;
    #pragma unroll
    for (int r = 0; r < 4; ++r)
      *(unsigned short*)(pb_ + qi * 80 + (lg * 4 + r) * 2) = f2bf(st[6 + b][r] * inv[b]);
    *(uint2*)(pb_ + qi * 80 + 32 + lg * 8) = make_uint2(0u, 0u);
  }
  asm volatile("" ::: "memory");
  #pragma unroll
  for (int b = 0; b < 3; ++b) {
    bf16x8 pf = ld16(pb_ + (b * 16 + ql) * 80 + lg * 16);
    ot[b]     = __builtin_amdgcn_mfma_f32_16x16x32_bf16(vC, pf, ot[b], 0, 0, 0);
    ot[3 + b] = __builtin_amdgcn_mfma_f32_16x16x32_bf16(vD, pf, ot[3 + b], 0, 0, 0);
  }

  // O store (Og aliases kg: wait for ALL waves' k reads to be consumed)
  __syncthreads();
  #pragma unroll
  for (int dm = 0; dm < 2; ++dm)
    #pragma unroll
    for (int b = 0; b < 3; ++b) {
      int qi = b * 16 + ql;
      if (b == 2 && ql >= 8) continue;   // tokens >= 40 don't exist
      unsigned u0 = pk2(ot[dm * 3 + b][0], ot[dm * 3 + b][1]);
      unsigned u1 = pk2(ot[dm * 3 + b][2], ot[dm * 3 + b][3]);
      int tg = w * 40 + qi;
      int colb = (h * 32 + dm * 16 + lg * 4) * 2;
      *(uint2*)(Og + (size_t)tg * 512 + (colb ^ (((tg >> 1) & 3) << 4))) = make_uint2(u0, u1);
    }
}

// ---- kernel 3: proj GEMM (M=163840, N=256, K=256), all-gll16 dbuf ----
#define P3_A0 0
#define P3_A1 8192
#define P3_B0 16384
#define P3_B1 32768
#define P3_LDS 49152

__global__ __launch_bounds__(512, 4)
void octa_proj(const char* __restrict__ Og, const unsigned short* __restrict__ pTq,
               const float* __restrict__ proj_b, float* __restrict__ out)
{
  extern __shared__ char smem[];
  const int tid = threadIdx.x, lane = tid & 63, wid = tid >> 6;
  const int ql = lane & 15, lg = lane >> 4;
  const int bm = blockIdx.x;
  const int wr = wid >> 2, wc = wid & 3;
  const char* pbase = (const char*)pTq;

  // prologue: stage A0 (1 slot/thread) + B0 (2/thread)
  gll16(Og + ((size_t)bm * 128 + (tid >> 2)) * 512 + (tid & 3) * 16,
        smem + P3_A0 + wid * 1024);
  #pragma unroll
  for (int it = 0; it < 2; ++it)
    gll16(pbase + (wid * 128 + it * 64 + lane) * 16, smem + P3_B0 + wid * 2048 + it * 1024);
  __syncthreads();

  f32x4 acc[4][4];
  #pragma unroll
  for (int m = 0; m < 4; ++m)
    #pragma unroll
    for (int n = 0; n < 4; ++n) acc[m][n] = (f32x4){0.f, 0.f, 0.f, 0.f};

  #pragma unroll
  for (int t = 0; t < 8; ++t) {
    if (t < 7) {
      char* ab1 = smem + (((t + 1) & 1) ? P3_A1 : P3_A0);
      char* bb1 = smem + (((t + 1) & 1) ? P3_B1 : P3_B0);
      gll16(Og + ((size_t)bm * 128 + (tid >> 2)) * 512 + (t + 1) * 64 + (tid & 3) * 16,
            ab1 + wid * 1024);
      #pragma unroll
      for (int it = 0; it < 2; ++it)
        gll16(pbase + (size_t)(t + 1) * 16384 + (wid * 128 + it * 64 + lane) * 16,
              bb1 + wid * 2048 + it * 1024);
    }
    const char* ab = smem + ((t & 1) ? P3_A1 : P3_A0);
    const char* bb = smem + ((t & 1) ? P3_B1 : P3_B0);
    bf16x8 af[4];
    #pragma unroll
    for (int mt = 0; mt < 4; ++mt) {
      int row = wr * 64 + mt * 16 + ql;
      af[mt] = ld16(ab + row * 64 + ((lg * 16) ^ (((row >> 1) & 3) << 4)));
    }
    #pragma unroll
    for (int nt = 0; nt < 4; ++nt) {
      int n = wc * 64 + nt * 16 + ql;
      bf16x8 bf = ld16(bb + n * 64 + ((lg * 16) ^ (((n >> 1) & 3) << 4)));
      #pragma unroll
      for (int mt = 0; mt < 4; ++mt)
        acc[mt][nt] = __builtin_amdgcn_mfma_f32_16x16x32_bf16(af[mt], bf, acc[mt][nt], 0, 0, 0);
    }
    __syncthreads();
  }

  #pragma unroll
  for (int nt = 0; nt < 4; ++nt) {
    int col = wc * 64 + nt * 16 + ql;
    float pb = proj_b[col];
    #pragma unroll
    for (int mt = 0; mt < 4; ++mt)
      #pragma unroll
      for (int r = 0; r < 4; ++r) {
        int tg = bm * 128 + wr * 64 + mt * 16 + lg * 4 + r;
        out[(size_t)tg * 256 + col] = acc[mt][nt][r] + pb;
      }
  }
}

// ---- std finalize (shared by both paths) ----
__global__ void octa_std(const float* __restrict__ ws, float* __restrict__ out,
                         int total_rows, size_t off)
{
  int j = blockIdx.x * 256 + threadIdx.x;
  if (j < 768) {
    float s = ws[j], ss = ws[768 + j];
    float T = (float)total_rows;
    float var = (ss - s * s / T) / (T - 1.f);
    out[off + j] = sqrtf(fmaxf(var, 0.f));
  }
}

// =======================================================================
// FALLBACK PATH: round-4 fused kernel (verified), used if ws too small
// =======================================================================
#define O_RPE 0
#define O_MSK 4896
#define O_IDX 8096
#define O_A   12192
#define O_ATT 36768
#define B1_SZ 49152
#define ATT_STRIDE 11776
#define AK 3840
#define AV 7680
#define B2_S (O_ATT + 94208)
#define B2_A O_ATT
#define LDS_BYTES_V4 163744

__device__ __forceinline__ int a_addr(int row, int byte) {
  return O_A + row * 512 + (byte ^ ((row & 7) << 4));
}
__device__ __forceinline__ int v_addr(int d, int byte) {
  return AV + d * 128 + (byte ^ ((d & 7) << 4));
}

__global__ void octa_prep_v4(const float* __restrict__ qkv_w, const float* __restrict__ proj_w,
                             unsigned short* __restrict__ wTq, unsigned short* __restrict__ pTq)
{
  int idx = blockIdx.x * 256 + threadIdx.x;
  if (idx < 196608) {
    int n = idx >> 8, k = idx & 255;
    wTq[idx] = f2bf(qkv_w[k * 768 + n]);
  } else {
    int i = idx - 196608;
    int n = i >> 8, k = i & 255;
    pTq[i] = f2bf(proj_w[k * 256 + n]);
  }
}

__global__ __launch_bounds__(512, 2)
void octa_main_v4(const float* __restrict__ data, const int* __restrict__ rel_pos,
                  const float* __restrict__ maskp, const float* __restrict__ qkv_b,
                  const float* __restrict__ proj_b, const float* __restrict__ rpe_table,
                  const unsigned short* __restrict__ wTq, const unsigned short* __restrict__ pTq,
                  float* __restrict__ ws, float* __restrict__ out)
{
  extern __shared__ char smem[];
  float* s_rpe = (float*)(smem + O_RPE);
  const int tid = threadIdx.x;
  const int w   = blockIdx.x;
  const int wid = tid >> 6;
  const int lane = tid & 63;
  const int ql = lane & 15;
  const int lg = lane >> 4;
  const int h  = wid;
  const int ab = O_ATT + wid * ATT_STRIDE;

  {
    #pragma unroll
    for (int it = 0; it < 6; ++it) {
      int g = it * 512 + tid;
      int n = g >> 2, slot = g & 3;
      const char* src = (const char*)wTq + (size_t)n * 512 + ((slot * 16) ^ ((n & 3) << 4));
      gll16(src, smem + O_ATT + it * 8192 + wid * 1024);
    }
  }
  for (int f = tid; f < 1224; f += 512) s_rpe[f] = rpe_table[f];
  for (int f = tid; f < 400; f += 512) {
    float4 m4 = ((const float4*)(maskp + (size_t)w * 1600))[f];
    uint2 pk;
    pk.x = pk2(m4.x, m4.y); pk.y = pk2(m4.z, m4.w);
    *(uint2*)(smem + O_MSK + f * 8) = pk;
  }
  for (int p = tid; p < 1024; p += 512) {
    const int* rp = rel_pos + ((size_t)w * 1024 + p) * 3;
    int c0 = rp[0], c1 = rp[1], c2 = rp[2];
    c0 = min(25, max(-25, c0)); c1 = min(25, max(-25, c1)); c2 = min(25, max(-25, c2));
    unsigned pk = (unsigned)(c0 + 25) | ((unsigned)(c1 + 76) << 10) | ((unsigned)(c2 + 127) << 20);
    *(unsigned*)(smem + O_IDX + ((p * 4) ^ (((p >> 5) & 7) << 4))) = pk;
  }
  {
    const float4* src = (const float4*)(data + (size_t)w * 10240);
    for (int f = tid; f < 2560; f += 512) {
      int token = f >> 6, q4 = f & 63;
      float4 d4 = src[f];
      uint2 pk;
      pk.x = pk2(d4.x, d4.y); pk.y = pk2(d4.z, d4.w);
      *(uint2*)(smem + a_addr(token, q4 * 8)) = pk;
    }
    int token = 40 + (tid >> 6), byte = (tid & 63) * 8;
    *(uint2*)(smem + a_addr(token, byte)) = make_uint2(0u, 0u);
  }
  __syncthreads();

  f32x4 acc[18];
  #pragma unroll
  for (int i = 0; i < 18; ++i) acc[i] = (f32x4){0.f, 0.f, 0.f, 0.f};

  for (int t = 0; t < 8; ++t) {
    if (t < 7) {
      int bb = O_ATT + ((t + 1) & 1) * B1_SZ;
      #pragma unroll
      for (int it = 0; it < 6; ++it) {
        int g = it * 512 + tid;
        int n = g >> 2, slot = g & 3;
        const char* src = (const char*)wTq + (size_t)n * 512 + (t + 1) * 64
                          + ((slot * 16) ^ ((n & 3) << 4));
        gll16(src, smem + bb + it * 8192 + wid * 1024);
      }
    }
    const int bb = O_ATT + (t & 1) * B1_SZ;
    bf16x8 af[3];
    #pragma unroll
    for (int mt = 0; mt < 3; ++mt)
      af[mt] = ld16(smem + a_addr(mt * 16 + ql, t * 64 + lg * 16));
    #pragma unroll
    for (int j = 0; j < 6; ++j) {
      int n = ((j >> 1) * 16 + 2 * wid + (j & 1)) * 16 + ql;
      bf16x8 bf = ld16(smem + bb + n * 64 + ((lg * 16) ^ ((n & 3) << 4)));
      #pragma unroll
      for (int mt = 0; mt < 3; ++mt)
        acc[j * 3 + mt] = __builtin_amdgcn_mfma_f32_16x16x32_bf16(af[mt], bf, acc[j * 3 + mt], 0, 0, 0);
    }
    __syncthreads();
  }

  {
    #pragma unroll
    for (int it = 0; it < 4; ++it) {
      int g = it * 512 + tid;
      int n = g >> 3, slot = g & 7;
      const char* src = (const char*)pTq + (size_t)n * 512 + ((slot * 16) ^ ((n & 7) << 4));
      gll16(src, smem + B2_S + it * 8192 + wid * 1024);
    }
  }

  #pragma unroll
  for (int j = 0; j < 6; ++j) {
    int sec = j >> 1;
    int ncol = sec * 256 + 32 * wid + (j & 1) * 16 + ql;
    int d = (j & 1) * 16 + ql;
    float bias = qkv_b[ncol];
    float s1 = 0.f, s2 = 0.f;
    #pragma unroll
    for (int mt = 0; mt < 3; ++mt) {
      #pragma unroll
      for (int r = 0; r < 4; ++r) {
        int token = mt * 16 + lg * 4 + r;
        float v = acc[j * 3 + mt][r] + bias;
        if (token < 40) { s1 += v; s2 += v * v; }
        if (sec == 0)
          *(unsigned short*)(smem + ab + token * 80 + d * 2) = f2bf(v * SCALE_F);
        else if (sec == 1)
          *(unsigned short*)(smem + ab + AK + token * 80 + d * 2) = f2bf(v);
        else
          *(unsigned short*)(smem + ab + v_addr(d, token * 2)) = f2bf(v);
      }
    }
    s1 += __shfl_xor(s1, 16); s1 += __shfl_xor(s1, 32);
    s2 += __shfl_xor(s2, 16); s2 += __shfl_xor(s2, 32);
    if (lg == 0) { atomicAdd(ws + ncol, s1); atomicAdd(ws + 768 + ncol, s2); }
  }
  {
    int zd = lane >> 1;
    int zb = 96 + (lane & 1) * 16;
    *(int4*)(smem + ab + v_addr(zd, zb)) = (int4){0, 0, 0, 0};
  }
  asm volatile("" ::: "memory");

  f32x4 st[9];
  {
    bf16x8 kf[3], qf[3];
    #pragma unroll
    for (int a = 0; a < 3; ++a) kf[a] = ld16(smem + ab + AK + (a * 16 + ql) * 80 + lg * 16);
    #pragma unroll
    for (int b = 0; b < 3; ++b) qf[b] = ld16(smem + ab + (b * 16 + ql) * 80 + lg * 16);
    #pragma unroll
    for (int a = 0; a < 3; ++a)
      #pragma unroll
      for (int b = 0; b < 3; ++b)
        st[a * 3 + b] = __builtin_amdgcn_mfma_f32_16x16x32_bf16(
            kf[a], qf[b], (f32x4){0.f, 0.f, 0.f, 0.f}, 0, 0, 0);
  }

  float mx[3] = {-3e38f, -3e38f, -3e38f};
  #pragma unroll
  for (int a = 0; a < 3; ++a) {
    #pragma unroll
    for (int b = 0; b < 3; ++b) {
      #pragma unroll
      for (int r = 0; r < 4; ++r) {
        int kj = a * 16 + lg * 4 + r;
        int qi = b * 16 + ql;
        float s = st[a * 3 + b][r];
        if (kj < 40) {
          if (qi < 40) {
            s += bf2f(*(const unsigned short*)(smem + O_MSK + (qi * 40 + kj) * 2));
            if (kj >= 8 && qi >= 8) {
              int p = (qi - 8) * 32 + (kj - 8);
              unsigned pk = *(const unsigned*)(smem + O_IDX + ((p * 4) ^ (((p >> 5) & 7) << 4)));
              s += s_rpe[(pk & 1023) * 8 + h] + s_rpe[((pk >> 10) & 1023) * 8 + h]
                 + s_rpe[(pk >> 20) * 8 + h];
            }
          }
        } else {
          s = -1e30f;
        }
        st[a * 3 + b][r] = s;
        mx[b] = fmaxf(mx[b], s);
      }
    }
  }
  #pragma unroll
  for (int b = 0; b < 3; ++b) {
    mx[b] = fmaxf(mx[b], __shfl_xor(mx[b], 16));
    mx[b] = fmaxf(mx[b], __shfl_xor(mx[b], 32));
  }
  float sum[3] = {0.f, 0.f, 0.f};
  #pragma unroll
  for (int a = 0; a < 3; ++a)
    #pragma unroll
    for (int b = 0; b < 3; ++b)
      #pragma unroll
      for (int r = 0; r < 4; ++r) {
        float e = __expf(st[a * 3 + b][r] - mx[b]);
        st[a * 3 + b][r] = e;
        sum[b] += e;
      }
  float inv[3];
  #pragma unroll
  for (int b = 0; b < 3; ++b) {
    sum[b] += __shfl_xor(sum[b], 16);
    sum[b] += __shfl_xor(sum[b], 32);
    inv[b] = 1.f / sum[b];
  }

  f32x4 ot[6];
  #pragma unroll
  for (int i = 0; i < 6; ++i) ot[i] = (f32x4){0.f, 0.f, 0.f, 0.f};

  #pragma unroll
  for (int a = 0; a < 2; ++a)
    #pragma unroll
    for (int b = 0; b < 3; ++b)
      #pragma unroll
      for (int r = 0; r < 4; ++r) {
        int kj = a * 16 + lg * 4 + r, qi = b * 16 + ql;
        *(unsigned short*)(smem + ab + qi * 80 + kj * 2) = f2bf(st[a * 3 + b][r] * inv[b]);
      }
  asm volatile("" ::: "memory");
  {
    bf16x8 vf0 = ld16(smem + ab + v_addr(ql, lg * 16));
    bf16x8 vf1 = ld16(smem + ab + v_addr(16 + ql, lg * 16));
    #pragma unroll
    for (int b = 0; b < 3; ++b) {
      bf16x8 pf = ld16(smem + ab + (b * 16 + ql) * 80 + lg * 16);
      ot[b] = __builtin_amdgcn_mfma_f32_16x16x32_bf16(vf0, pf, ot[b], 0, 0, 0);
      ot[3 + b] = __builtin_amdgcn_mfma_f32_16x16x32_bf16(vf1, pf, ot[3 + b], 0, 0, 0);
    }
  }
  asm volatile("" ::: "memory");
  #pragma unroll
  for (int b = 0; b < 3; ++b) {
    int qi = b * 16 + ql;
    #pragma unroll
    for (int r = 0; r < 4; ++r) {
      int kj = 32 + lg * 4 + r;
      *(unsigned short*)(smem + ab + qi * 80 + (kj - 32) * 2) = f2bf(st[6 + b][r] * inv[b]);
    }
    *(uint2*)(smem + ab + qi * 80 + 32 + lg * 8) = make_uint2(0u, 0u);
  }
  asm volatile("" ::: "memory");
  {
    bf16x8 vf0 = ld16(smem + ab + v_addr(ql, 64 + lg * 16));
    bf16x8 vf1 = ld16(smem + ab + v_addr(16 + ql, 64 + lg * 16));
    #pragma unroll
    for (int b = 0; b < 3; ++b) {
      bf16x8 pf = ld16(smem + ab + (b * 16 + ql) * 80 + lg * 16);
      ot[b] = __builtin_amdgcn_mfma_f32_16x16x32_bf16(vf0, pf, ot[b], 0, 0, 0);
      ot[3 + b] = __builtin_amdgcn_mfma_f32_16x16x32_bf16(vf1, pf, ot[3 + b], 0, 0, 0);
    }
  }
  #pragma unroll
  for (int dm = 0; dm < 2; ++dm)
    #pragma unroll
    for (int b = 0; b < 3; ++b)
      #pragma unroll
      for (int r = 0; r < 4; ++r) {
        int d = dm * 16 + lg * 4 + r;
        int qi = b * 16 + ql;
        *(unsigned short*)(smem + a_addr(qi, (h * 32 + d) * 2)) = f2bf(ot[dm * 3 + b][r]);
      }
  __syncthreads();

  f32x4 oacc[6];
  #pragma unroll
  for (int i = 0; i < 6; ++i) oacc[i] = (f32x4){0.f, 0.f, 0.f, 0.f};

  for (int t = 0; t < 4; ++t) {
    if (t < 3) {
      int bb = ((t + 1) & 1) ? B2_A : B2_S;
      #pragma unroll
      for (int it = 0; it < 4; ++it) {
        int g = it * 512 + tid;
        int n = g >> 3, slot = g & 7;
        const char* src = (const char*)pTq + (size_t)n * 512 + (t + 1) * 128
                          + ((slot * 16) ^ ((n & 7) << 4));
        gll16(src, smem + bb + it * 8192 + wid * 1024);
      }
    }
    const int bb = (t & 1) ? B2_A : B2_S;
    #pragma unroll
    for (int ks = 0; ks < 2; ++ks) {
      bf16x8 af[3];
      #pragma unroll
      for (int mt = 0; mt < 3; ++mt)
        af[mt] = ld16(smem + a_addr(mt * 16 + ql, t * 128 + ks * 64 + lg * 16));
      #pragma unroll
      for (int nt = 0; nt < 2; ++nt) {
        int n = (2 * wid + nt) * 16 + ql;
        bf16x8 bf = ld16(smem + bb + n * 128 + ((ks * 64 + lg * 16) ^ ((n & 7) << 4)));
        #pragma unroll
        for (int mt = 0; mt < 3; ++mt)
          oacc[nt * 3 + mt] = __builtin_amdgcn_mfma_f32_16x16x32_bf16(af[mt], bf, oacc[nt * 3 + mt], 0, 0, 0);
      }
    }
    __syncthreads();
  }

  #pragma unroll
  for (int nt = 0; nt < 2; ++nt) {
    int ncol = (2 * wid + nt) * 16 + ql;
    float pb = proj_b[ncol];
    #pragma unroll
    for (int mt = 0; mt < 3; ++mt)
      #pragma unroll
      for (int r = 0; r < 4; ++r) {
        int token = mt * 16 + lg * 4 + r;
        if (token < 40)
          out[(size_t)w * 10240 + token * 256 + ncol] = oacc[nt * 3 + mt][r] + pb;
      }
  }
}

// =======================================================================
extern "C" void kernel_launch(void* const* d_in, const int* in_sizes, int n_in,
                              void* d_out, int out_size, void* d_ws, size_t ws_size,
                              hipStream_t stream) {
  const float* data    = (const float*)d_in[0];
  const int*   rel_pos = (const int*)d_in[1];
  const float* maskp   = (const float*)d_in[2];
  const float* qkv_w   = (const float*)d_in[3];
  const float* qkv_b   = (const float*)d_in[4];
  const float* proj_w  = (const float*)d_in[5];
  const float* proj_b  = (const float*)d_in[6];
  const float* rpe_tab = (const float*)d_in[7];
  float* out = (float*)d_out;
  float* ws  = (float*)d_ws;

  const int nw = in_sizes[1] / 3072;           // 4096
  const int total_rows = nw * 40;
  const size_t std_off = (size_t)nw * 10240;

  // ws layout (new path): [0,6144) sums | wTq 393216 | pTq 131072 | k/O 83886080
  const size_t WS_NEED = 530432ull + 83886080ull;

  unsigned short* wTq = (unsigned short*)((char*)d_ws + 6144);
  unsigned short* pTq = (unsigned short*)((char*)d_ws + 399360);

  hipMemsetAsync(ws, 0, 6144, stream);

  if (ws_size >= WS_NEED) {
    char* kg = (char*)d_ws + 530432;
    char* Og = kg;                               // O overwrites k (dead after attn reads)
    char* qg = (char*)d_out;                     // q in d_out[0, 83886080)
    char* vg = (char*)d_out + 83886080;          // vT in d_out[83886080, 167772160)

    hipLaunchKernelGGL(octa_prep2, dim3(1024), dim3(256), 0, stream, qkv_w, proj_w, wTq, pTq);
    hipLaunchKernelGGL(octa_qkv, dim3(nw * 40 / 32), dim3(512), KQ_LDS, stream,
                       data, qkv_b, wTq, ws, qg, kg, vg);
    hipLaunchKernelGGL(octa_attn, dim3(nw), dim3(512), A2_LDS, stream,
                       qg, kg, vg, maskp, rel_pos, rpe_tab, Og);
    hipLaunchKernelGGL(octa_proj, dim3(nw * 40 / 128), dim3(512), P3_LDS, stream,
                       Og, pTq, proj_b, out);
    hipLaunchKernelGGL(octa_std, dim3(3), dim3(256), 0, stream, ws, out, total_rows, std_off);
  } else {
    hipLaunchKernelGGL(octa_prep_v4, dim3(1024), dim3(256), 0, stream, qkv_w, proj_w, wTq, pTq);
    (void)hipFuncSetAttribute((const void*)octa_main_v4,
                              hipFuncAttributeMaxDynamicSharedMemorySize, LDS_BYTES_V4);
    hipLaunchKernelGGL(octa_main_v4, dim3(nw), dim3(512), LDS_BYTES_V4, stream,
                       data, rel_pos, maskp, qkv_b, proj_b, rpe_tab, wTq, pTq, ws, out);
    hipLaunchKernelGGL(octa_std, dim3(3), dim3(256), 0, stream, ws, out, total_rows, std_off);
  }
}

// Round 8
// 399.078 us; speedup vs baseline: 1.2661x; 1.2661x over previous
//
#include <hip/hip_runtime.h>
#include <math.h>

// OctreeAttention: C=256, H=8, HD=32, K=32, G=8, W=40, NW=4096, RPE rows=153
#define SCALE_F 0.17677669529663687f  // 32^-0.5

typedef __bf16 bf16x8 __attribute__((ext_vector_type(8)));
typedef float f32x4 __attribute__((ext_vector_type(4)));

__device__ __forceinline__ unsigned short f2bf(float f) {
  unsigned u = __builtin_bit_cast(unsigned, f);
  u = (u + 0x7FFFu + ((u >> 16) & 1u)) >> 16;
  return (unsigned short)u;
}
__device__ __forceinline__ float bf2f(unsigned short u) {
  return __builtin_bit_cast(float, (unsigned)u << 16);
}
__device__ __forceinline__ unsigned pk2(float a, float b) {
  return (unsigned)f2bf(a) | ((unsigned)f2bf(b) << 16);
}
__device__ __forceinline__ bf16x8 ld16(const void* p) {
  int4 v = *(const int4*)p;
  return __builtin_bit_cast(bf16x8, v);
}
__device__ __forceinline__ void gll16(const void* g, void* l) {
  __builtin_amdgcn_global_load_lds(
      (const __attribute__((address_space(1))) unsigned int*)g,
      (__attribute__((address_space(3))) unsigned int*)l, 16, 0, 0);
}

// =======================================================================
// NEW PATH: 4-kernel split (needs ws_size >= 84.5 MB)
// =======================================================================

// ---- prep: weights -> bf16 ----
// wTq: chunked PRE-SWIZZLED layout (R5-verified): chunk (nh,kc) = 24576 B =
// [384 n][64 B]; byte (n*64+cb) holds wT[n][kc*32 + ((cb ^ ((n>>1)&3)<<4)>>1)].
// pTq: pre-swizzled chunked layout for octa_proj's gll16 staging.
__global__ void octa_prep2(const float* __restrict__ qkv_w, const float* __restrict__ proj_w,
                           unsigned short* __restrict__ wTq, unsigned short* __restrict__ pTq)
{
  int e = blockIdx.x * 256 + threadIdx.x;   // 262144
  if (e < 196608) {
    int nh = e / 98304, rr = e % 98304;
    int kc = rr / 12288, p2 = rr % 12288;
    int n = p2 >> 5, cw = p2 & 31;
    int kl = cw ^ (((n >> 1) & 3) << 3);
    wTq[e] = f2bf(qkv_w[(size_t)(kc * 32 + kl) * 768 + nh * 384 + n]);
  } else {
    int e2 = e - 196608;
    int kc = e2 >> 13, p2 = e2 & 8191;
    int n = p2 >> 5, cw = p2 & 31;
    int kl = cw ^ (((n >> 1) & 3) << 3);
    pTq[e2] = f2bf(proj_w[(size_t)(kc * 32 + kl) * 256 + n]);
  }
}

// ---- kernel 1: qkv GEMM (M=163840, N=384/block, K=256) ----
// grid 5120 (bm = bid>>1: 64 rows, nh = bid&1: 384 cols), 512 thr, 8 waves 2Mx4N.
// A: staged to LDS once (64x256 bf16, swz). B: gll16 dbuf (R5-verified pattern).
// Epilogue: acc -> LDS E[64 tok][384 col] -> coalesced dwordx4 global stores.
// q/k/v ALL stored as [w][h][tk][d] bf16 (2560 B slices).
#define KQ_A  0         // 32768
#define KQ_B0 32768     // 24576
#define KQ_B1 57344     // 24576
#define KQ_E  32768     // 49152 (reuses B0+B1)
#define KQ_LDS 81920

__global__ __launch_bounds__(512, 4)
void octa_qkv(const float* __restrict__ data, const float* __restrict__ qkv_b,
              const unsigned short* __restrict__ wTq, float* __restrict__ ws,
              char* __restrict__ qg, char* __restrict__ kg, char* __restrict__ vg)
{
  extern __shared__ char smem[];
  const int tid = threadIdx.x, lane = tid & 63, wid = tid >> 6;
  const int ql = lane & 15, lg = lane >> 4;
  const int bm = blockIdx.x >> 1, nh = blockIdx.x & 1;
  const int wr = wid >> 2, wc = wid & 3;
  const char* wbase = (const char*)wTq + (size_t)nh * 196608;

  // prologue: issue B0 staging, then stage A (latency of both overlaps)
  #pragma unroll
  for (int it = 0; it < 3; ++it)
    gll16(wbase + wid * 3072 + it * 1024 + lane * 16,
          smem + KQ_B0 + wid * 3072 + it * 1024);
  {
    const float4* src = (const float4*)(data + (size_t)bm * 64 * 256);
    #pragma unroll
    for (int rep = 0; rep < 8; ++rep) {
      int f = rep * 512 + tid;          // 4096 float4 = 64 rows x 64
      int row = f >> 6, q4 = f & 63;
      float4 d4 = src[f];
      *(uint2*)(smem + KQ_A + row * 512 + ((q4 * 8) ^ ((row & 7) << 4))) =
          make_uint2(pk2(d4.x, d4.y), pk2(d4.z, d4.w));
    }
  }
  __syncthreads();

  f32x4 acc[2][6];
  #pragma unroll
  for (int m = 0; m < 2; ++m)
    #pragma unroll
    for (int n = 0; n < 6; ++n) acc[m][n] = (f32x4){0.f, 0.f, 0.f, 0.f};

  #pragma unroll
  for (int t = 0; t < 8; ++t) {
    if (t < 7) {
      char* bb1 = smem + (((t + 1) & 1) ? KQ_B1 : KQ_B0);
      #pragma unroll
      for (int it = 0; it < 3; ++it)
        gll16(wbase + (size_t)(t + 1) * 24576 + wid * 3072 + it * 1024 + lane * 16,
              bb1 + wid * 3072 + it * 1024);
    }
    const char* bb = smem + ((t & 1) ? KQ_B1 : KQ_B0);
    bf16x8 af[2];
    #pragma unroll
    for (int mt = 0; mt < 2; ++mt) {
      int row = wr * 32 + mt * 16 + ql;
      af[mt] = ld16(smem + KQ_A + row * 512 + ((t * 64 + lg * 16) ^ ((row & 7) << 4)));
    }
    #pragma unroll
    for (int nt = 0; nt < 6; ++nt) {
      int n = wc * 96 + nt * 16 + ql;
      bf16x8 bf = ld16(bb + n * 64 + ((lg * 16) ^ (((n >> 1) & 3) << 4)));
      acc[0][nt] = __builtin_amdgcn_mfma_f32_16x16x32_bf16(af[0], bf, acc[0][nt], 0, 0, 0);
      acc[1][nt] = __builtin_amdgcn_mfma_f32_16x16x32_bf16(af[1], bf, acc[1][nt], 0, 0, 0);
    }
    __syncthreads();
  }

  // ---- epilogue phase 1: bias + std partials + write acc into E (LDS) ----
  // E[tok 64][col 384] bf16, row stride 768 B, byte = (col*2) ^ ((tok&7)<<4)
  #pragma unroll
  for (int nt = 0; nt < 6; ++nt) {
    int col_l = wc * 96 + nt * 16 + ql;
    int gcol = nh * 384 + col_l;
    int tensor = gcol >> 8;
    float bias = qkv_b[gcol];
    float s1 = 0.f, s2 = 0.f;
    #pragma unroll
    for (int mt = 0; mt < 2; ++mt)
      #pragma unroll
      for (int r = 0; r < 4; ++r) {
        int tok = wr * 32 + mt * 16 + lg * 4 + r;
        float v = acc[mt][nt][r] + bias;
        s1 += v; s2 += v * v;
        float sv = (tensor == 0) ? v * SCALE_F : v;
        *(unsigned short*)(smem + KQ_E + tok * 768 + ((col_l * 2) ^ ((tok & 7) << 4))) = f2bf(sv);
      }
    s1 += __shfl_xor(s1, 16); s1 += __shfl_xor(s1, 32);
    s2 += __shfl_xor(s2, 16); s2 += __shfl_xor(s2, 32);
    if (lg == 0) { atomicAdd(ws + gcol, s1); atomicAdd(ws + 768 + gcol, s2); }
  }
  __syncthreads();

  // ---- epilogue phase 2: coalesced read-out, 16 B dense stores ----
  #pragma unroll
  for (int rep = 0; rep < 6; ++rep) {
    int c = rep * 512 + tid;            // [0, 3072): tok*48 + cc
    int tok_l = c / 48, cc = c - tok_l * 48;
    int4 val = *(const int4*)(smem + KQ_E + tok_l * 768 + ((cc * 16) ^ ((tok_l & 7) << 4)));
    int gcol0 = nh * 384 + cc * 8;      // 8-col chunk, never crosses 256-boundary
    int tensor = gcol0 >> 8, h = (gcol0 >> 5) & 7, d0 = gcol0 & 31;
    int tg = bm * 64 + tok_l, w = tg / 40, tk = tg - w * 40;
    size_t slice = (size_t)(w * 8 + h) * 2560;
    char* base = tensor == 0 ? qg : (tensor == 1 ? kg : vg);
    *(int4*)(base + slice + tk * 64 + d0 * 2) = val;
  }
}

// ---- kernel 2: attention, 1 window/block, 8 head-waves, q/k/v direct-from-global ----
// q,k,v all [w][h][tk][d]; vT fragments built by scalar gather (L2-hot slice).
#define A2_MSK 0       // mask^T bf16 [40 kj][104 B rows]
#define A2_IDX 4160    // packed idx [32 kj][128 B], XOR bit6 by kj&1
#define A2_RPT 8256    // rpeT f32 [8 h][160]
#define A2_P   13376   // per-wave P [48][80 B] x8 = 30720
#define A2_LDS 44096

__global__ __launch_bounds__(512, 4)
void octa_attn(const char* __restrict__ qg, const char* __restrict__ kg,
               const char* __restrict__ vg, const float* __restrict__ maskp,
               const int* __restrict__ rel_pos, const float* __restrict__ rpe_table,
               char* __restrict__ Og)
{
  extern __shared__ char smem[];
  const int tid = threadIdx.x, w = blockIdx.x, wid = tid >> 6;
  const int lane = tid & 63, ql = lane & 15, lg = lane >> 4, h = wid;
  const int perm = ql * 64 + lg * 16;
  const char* qb = qg + (size_t)(w * 8 + h) * 2560;
  const char* kb = kg + (size_t)(w * 8 + h) * 2560;
  const char* vb = vg + (size_t)(w * 8 + h) * 2560;

  // issue all fragment loads up-front (latency hides under phase-0 staging)
  bf16x8 kf0 = ld16(kb + perm), kf1 = ld16(kb + 1024 + perm), kf2 = ld16(kb + 2048 + perm);
  bf16x8 qf0 = ld16(qb + perm), qf1 = ld16(qb + 1024 + perm), qf2 = ld16(qb + 2048 + perm);
  // vT fragments via scalar gather: A[d][tok]; vA/vB toks 0..31, vC/vD toks 32..39
  union U8 { unsigned short u[8]; bf16x8 v; };
  U8 ua, ub, uc, ud;
  #pragma unroll
  for (int j = 0; j < 8; ++j) {
    int tok = lg * 8 + j;
    ua.u[j] = *(const unsigned short*)(vb + tok * 64 + ql * 2);
    ub.u[j] = *(const unsigned short*)(vb + tok * 64 + (16 + ql) * 2);
  }
  if (lg == 0) {
    #pragma unroll
    for (int j = 0; j < 8; ++j) {
      uc.u[j] = *(const unsigned short*)(vb + (32 + j) * 64 + ql * 2);
      ud.u[j] = *(const unsigned short*)(vb + (32 + j) * 64 + (16 + ql) * 2);
    }
  } else {
    #pragma unroll
    for (int j = 0; j < 8; ++j) { uc.u[j] = 0; ud.u[j] = 0; }
  }
  bf16x8 vA = ua.v, vB = ub.v, vC = uc.v, vD = ud.v;

  // phase 0: stage mask^T, packed idx, transposed rpe
  for (int f = tid; f < 1600; f += 512) {
    float m = maskp[(size_t)w * 1600 + f];
    int qi = f / 40, kj = f - qi * 40;
    *(unsigned short*)(smem + A2_MSK + kj * 104 + qi * 2) = f2bf(m);
  }
  for (int f = tid; f < 1024; f += 512) {
    const int* rp = rel_pos + ((size_t)w * 1024 + f) * 3;
    int c0 = rp[0], c1 = rp[1], c2 = rp[2];
    c0 = min(25, max(-25, c0)); c1 = min(25, max(-25, c1)); c2 = min(25, max(-25, c2));
    unsigned pk = (unsigned)(c0 + 25) | ((unsigned)(c1 + 76) << 10) | ((unsigned)(c2 + 127) << 20);
    int qi8 = f >> 5, kj8 = f & 31;
    *(unsigned*)(smem + A2_IDX + kj8 * 128 + ((qi8 * 4) ^ ((kj8 & 1) << 6))) = pk;
  }
  for (int f = tid; f < 1224; f += 512)
    *(float*)(smem + A2_RPT + (((f & 7) * 160 + (f >> 3)) << 2)) = rpe_table[f];
  __syncthreads();

  // QK^T: ST[kj][qi] = mfma(A=k, B=q)
  f32x4 st[9];
  {
    bf16x8 kf[3] = {kf0, kf1, kf2}, qf[3] = {qf0, qf1, qf2};
    #pragma unroll
    for (int a = 0; a < 3; ++a)
      #pragma unroll
      for (int b = 0; b < 3; ++b)
        st[a * 3 + b] = __builtin_amdgcn_mfma_f32_16x16x32_bf16(
            kf[a], qf[b], (f32x4){0.f, 0.f, 0.f, 0.f}, 0, 0, 0);
  }

  // logits + mask + rpe; per-column (qi) max
  float mx[3] = {-3e38f, -3e38f, -3e38f};
  #pragma unroll
  for (int a = 0; a < 3; ++a) {
    #pragma unroll
    for (int b = 0; b < 3; ++b) {
      #pragma unroll
      for (int r = 0; r < 4; ++r) {
        int kj = a * 16 + lg * 4 + r;
        int qi = b * 16 + ql;
        float s = st[a * 3 + b][r];
        if (kj < 40) {
          if (qi < 40) {
            s += bf2f(*(const unsigned short*)(smem + A2_MSK + kj * 104 + qi * 2));
            if (kj >= 8 && qi >= 8) {
              unsigned pk = *(const unsigned*)(smem + A2_IDX + (kj - 8) * 128 +
                                               (((qi - 8) * 4) ^ (((kj - 8) & 1) << 6)));
              s += *(const float*)(smem + A2_RPT + ((h * 160 + (pk & 1023)) << 2))
                 + *(const float*)(smem + A2_RPT + ((h * 160 + ((pk >> 10) & 1023)) << 2))
                 + *(const float*)(smem + A2_RPT + ((h * 160 + (pk >> 20)) << 2));
            }
          }
        } else {
          s = -1e30f;
        }
        st[a * 3 + b][r] = s;
        mx[b] = fmaxf(mx[b], s);
      }
    }
  }
  #pragma unroll
  for (int b = 0; b < 3; ++b) {
    mx[b] = fmaxf(mx[b], __shfl_xor(mx[b], 16));
    mx[b] = fmaxf(mx[b], __shfl_xor(mx[b], 32));
  }
  float sum[3] = {0.f, 0.f, 0.f};
  #pragma unroll
  for (int a = 0; a < 3; ++a)
    #pragma unroll
    for (int b = 0; b < 3; ++b)
      #pragma unroll
      for (int r = 0; r < 4; ++r) {
        float e = __expf(st[a * 3 + b][r] - mx[b]);
        st[a * 3 + b][r] = e;
        sum[b] += e;
      }
  float inv[3];
  #pragma unroll
  for (int b = 0; b < 3; ++b) {
    sum[b] += __shfl_xor(sum[b], 16);
    sum[b] += __shfl_xor(sum[b], 32);
    inv[b] = 1.f / sum[b];
  }

  // PV in two kj-halves; per-wave P buffer
  char* pb_ = smem + A2_P + wid * 3840;
  f32x4 ot[6];
  #pragma unroll
  for (int i = 0; i < 6; ++i) ot[i] = (f32x4){0.f, 0.f, 0.f, 0.f};

  #pragma unroll
  for (int a = 0; a < 2; ++a)
    #pragma unroll
    for (int b = 0; b < 3; ++b)
      #pragma unroll
      for (int r = 0; r < 4; ++r) {
        int kj = a * 16 + lg * 4 + r, qi = b * 16 + ql;
        *(unsigned short*)(pb_ + qi * 80 + kj * 2) = f2bf(st[a * 3 + b][r] * inv[b]);
      }
  asm volatile("" ::: "memory");
  #pragma unroll
  for (int b = 0; b < 3; ++b) {
    bf16x8 pf = ld16(pb_ + (b * 16 + ql) * 80 + lg * 16);
    ot[b]     = __builtin_amdgcn_mfma_f32_16x16x32_bf16(vA, pf, ot[b], 0, 0, 0);
    ot[3 + b] = __builtin_amdgcn_mfma_f32_16x16x32_bf16(vB, pf, ot[3 + b], 0, 0, 0);
  }
  asm volatile("" ::: "memory");
  #pragma unroll
  for (int b = 0; b < 3; ++b) {
    int qi = b * 16 + ql;
    #pragma unroll
    for (int r = 0; r < 4; ++r)
      *(unsigned short*)(pb_ + qi * 80 + (lg * 4 + r) * 2) = f2bf(st[6 + b][r] * inv[b]);
    *(uint2*)(pb_ + qi * 80 + 32 + lg * 8) = make_uint2(0u, 0u);
  }
  asm volatile("" ::: "memory");
  #pragma unroll
  for (int b = 0; b < 3; ++b) {
    bf16x8 pf = ld16(pb_ + (b * 16 + ql) * 80 + lg * 16);
    ot[b]     = __builtin_amdgcn_mfma_f32_16x16x32_bf16(vC, pf, ot[b], 0, 0, 0);
    ot[3 + b] = __builtin_amdgcn_mfma_f32_16x16x32_bf16(vD, pf, ot[3 + b], 0, 0, 0);
  }

  // O store (Og aliases kg: wait for ALL waves' k reads to be consumed)
  __syncthreads();
  #pragma unroll
  for (int dm = 0; dm < 2; ++dm)
    #pragma unroll
    for (int b = 0; b < 3; ++b) {
      int qi = b * 16 + ql;
      if (b == 2 && ql >= 8) continue;   // tokens >= 40 don't exist
      unsigned u0 = pk2(ot[dm * 3 + b][0], ot[dm * 3 + b][1]);
      unsigned u1 = pk2(ot[dm * 3 + b][2], ot[dm * 3 + b][3]);
      int tg = w * 40 + qi;
      int colb = (h * 32 + dm * 16 + lg * 4) * 2;
      *(uint2*)(Og + (size_t)tg * 512 + (colb ^ (((tg >> 1) & 3) << 4))) = make_uint2(u0, u1);
    }
}

// ---- kernel 3: proj GEMM (M=163840, N=256, K=256), all-gll16 dbuf ----
#define P3_A0 0
#define P3_A1 8192
#define P3_B0 16384
#define P3_B1 32768
#define P3_LDS 49152

__global__ __launch_bounds__(512, 4)
void octa_proj(const char* __restrict__ Og, const unsigned short* __restrict__ pTq,
               const float* __restrict__ proj_b, float* __restrict__ out)
{
  extern __shared__ char smem[];
  const int tid = threadIdx.x, lane = tid & 63, wid = tid >> 6;
  const int ql = lane & 15, lg = lane >> 4;
  const int bm = blockIdx.x;
  const int wr = wid >> 2, wc = wid & 3;
  const char* pbase = (const char*)pTq;

  // prologue: stage A0 (1 slot/thread) + B0 (2/thread)
  gll16(Og + ((size_t)bm * 128 + (tid >> 2)) * 512 + (tid & 3) * 16,
        smem + P3_A0 + wid * 1024);
  #pragma unroll
  for (int it = 0; it < 2; ++it)
    gll16(pbase + (wid * 128 + it * 64 + lane) * 16, smem + P3_B0 + wid * 2048 + it * 1024);
  __syncthreads();

  f32x4 acc[4][4];
  #pragma unroll
  for (int m = 0; m < 4; ++m)
    #pragma unroll
    for (int n = 0; n < 4; ++n) acc[m][n] = (f32x4){0.f, 0.f, 0.f, 0.f};

  #pragma unroll
  for (int t = 0; t < 8; ++t) {
    if (t < 7) {
      char* ab1 = smem + (((t + 1) & 1) ? P3_A1 : P3_A0);
      char* bb1 = smem + (((t + 1) & 1) ? P3_B1 : P3_B0);
      gll16(Og + ((size_t)bm * 128 + (tid >> 2)) * 512 + (t + 1) * 64 + (tid & 3) * 16,
            ab1 + wid * 1024);
      #pragma unroll
      for (int it = 0; it < 2; ++it)
        gll16(pbase + (size_t)(t + 1) * 16384 + (wid * 128 + it * 64 + lane) * 16,
              bb1 + wid * 2048 + it * 1024);
    }
    const char* ab = smem + ((t & 1) ? P3_A1 : P3_A0);
    const char* bb = smem + ((t & 1) ? P3_B1 : P3_B0);
    bf16x8 af[4];
    #pragma unroll
    for (int mt = 0; mt < 4; ++mt) {
      int row = wr * 64 + mt * 16 + ql;
      af[mt] = ld16(ab + row * 64 + ((lg * 16) ^ (((row >> 1) & 3) << 4)));
    }
    #pragma unroll
    for (int nt = 0; nt < 4; ++nt) {
      int n = wc * 64 + nt * 16 + ql;
      bf16x8 bf = ld16(bb + n * 64 + ((lg * 16) ^ (((n >> 1) & 3) << 4)));
      #pragma unroll
      for (int mt = 0; mt < 4; ++mt)
        acc[mt][nt] = __builtin_amdgcn_mfma_f32_16x16x32_bf16(af[mt], bf, acc[mt][nt], 0, 0, 0);
    }
    __syncthreads();
  }

  #pragma unroll
  for (int nt = 0; nt < 4; ++nt) {
    int col = wc * 64 + nt * 16 + ql;
    float pb = proj_b[col];
    #pragma unroll
    for (int mt = 0; mt < 4; ++mt)
      #pragma unroll
      for (int r = 0; r < 4; ++r) {
        int tg = bm * 128 + wr * 64 + mt * 16 + lg * 4 + r;
        out[(size_t)tg * 256 + col] = acc[mt][nt][r] + pb;
      }
  }
}

// ---- std finalize (shared by both paths) ----
__global__ void octa_std(const float* __restrict__ ws, float* __restrict__ out,
                         int total_rows, size_t off)
{
  int j = blockIdx.x * 256 + threadIdx.x;
  if (j < 768) {
    float s = ws[j], ss = ws[768 + j];
    float T = (float)total_rows;
    float var = (ss - s * s / T) / (T - 1.f);
    out[off + j] = sqrtf(fmaxf(var, 0.f));
  }
}

// =======================================================================
// FALLBACK PATH: round-4 fused kernel (verified), used if ws too small
// =======================================================================
#define O_RPE 0
#define O_MSK 4896
#define O_IDX 8096
#define O_A   12192
#define O_ATT 36768
#define B1_SZ 49152
#define ATT_STRIDE 11776
#define AK 3840
#define AV 7680
#define B2_S (O_ATT + 94208)
#define B2_A O_ATT
#define LDS_BYTES_V4 163744

__device__ __forceinline__ int a_addr(int row, int byte) {
  return O_A + row * 512 + (byte ^ ((row & 7) << 4));
}
__device__ __forceinline__ int v_addr(int d, int byte) {
  return AV + d * 128 + (byte ^ ((d & 7) << 4));
}

__global__ void octa_prep_v4(const float* __restrict__ qkv_w, const float* __restrict__ proj_w,
                             unsigned short* __restrict__ wTq, unsigned short* __restrict__ pTq)
{
  int idx = blockIdx.x * 256 + threadIdx.x;
  if (idx < 196608) {
    int n = idx >> 8, k = idx & 255;
    wTq[idx] = f2bf(qkv_w[k * 768 + n]);
  } else {
    int i = idx - 196608;
    int n = i >> 8, k = i & 255;
    pTq[i] = f2bf(proj_w[k * 256 + n]);
  }
}

__global__ __launch_bounds__(512, 2)
void octa_main_v4(const float* __restrict__ data, const int* __restrict__ rel_pos,
                  const float* __restrict__ maskp, const float* __restrict__ qkv_b,
                  const float* __restrict__ proj_b, const float* __restrict__ rpe_table,
                  const unsigned short* __restrict__ wTq, const unsigned short* __restrict__ pTq,
                  float* __restrict__ ws, float* __restrict__ out)
{
  extern __shared__ char smem[];
  float* s_rpe = (float*)(smem + O_RPE);
  const int tid = threadIdx.x;
  const int w   = blockIdx.x;
  const int wid = tid >> 6;
  const int lane = tid & 63;
  const int ql = lane & 15;
  const int lg = lane >> 4;
  const int h  = wid;
  const int ab = O_ATT + wid * ATT_STRIDE;

  {
    #pragma unroll
    for (int it = 0; it < 6; ++it) {
      int g = it * 512 + tid;
      int n = g >> 2, slot = g & 3;
      const char* src = (const char*)wTq + (size_t)n * 512 + ((slot * 16) ^ ((n & 3) << 4));
      gll16(src, smem + O_ATT + it * 8192 + wid * 1024);
    }
  }
  for (int f = tid; f < 1224; f += 512) s_rpe[f] = rpe_table[f];
  for (int f = tid; f < 400; f += 512) {
    float4 m4 = ((const float4*)(maskp + (size_t)w * 1600))[f];
    uint2 pk;
    pk.x = pk2(m4.x, m4.y); pk.y = pk2(m4.z, m4.w);
    *(uint2*)(smem + O_MSK + f * 8) = pk;
  }
  for (int p = tid; p < 1024; p += 512) {
    const int* rp = rel_pos + ((size_t)w * 1024 + p) * 3;
    int c0 = rp[0], c1 = rp[1], c2 = rp[2];
    c0 = min(25, max(-25, c0)); c1 = min(25, max(-25, c1)); c2 = min(25, max(-25, c2));
    unsigned pk = (unsigned)(c0 + 25) | ((unsigned)(c1 + 76) << 10) | ((unsigned)(c2 + 127) << 20);
    *(unsigned*)(smem + O_IDX + ((p * 4) ^ (((p >> 5) & 7) << 4))) = pk;
  }
  {
    const float4* src = (const float4*)(data + (size_t)w * 10240);
    for (int f = tid; f < 2560; f += 512) {
      int token = f >> 6, q4 = f & 63;
      float4 d4 = src[f];
      uint2 pk;
      pk.x = pk2(d4.x, d4.y); pk.y = pk2(d4.z, d4.w);
      *(uint2*)(smem + a_addr(token, q4 * 8)) = pk;
    }
    int token = 40 + (tid >> 6), byte = (tid & 63) * 8;
    *(uint2*)(smem + a_addr(token, byte)) = make_uint2(0u, 0u);
  }
  __syncthreads();

  f32x4 acc[18];
  #pragma unroll
  for (int i = 0; i < 18; ++i) acc[i] = (f32x4){0.f, 0.f, 0.f, 0.f};

  for (int t = 0; t < 8; ++t) {
    if (t < 7) {
      int bb = O_ATT + ((t + 1) & 1) * B1_SZ;
      #pragma unroll
      for (int it = 0; it < 6; ++it) {
        int g = it * 512 + tid;
        int n = g >> 2, slot = g & 3;
        const char* src = (const char*)wTq + (size_t)n * 512 + (t + 1) * 64
                          + ((slot * 16) ^ ((n & 3) << 4));
        gll16(src, smem + bb + it * 8192 + wid * 1024);
      }
    }
    const int bb = O_ATT + (t & 1) * B1_SZ;
    bf16x8 af[3];
    #pragma unroll
    for (int mt = 0; mt < 3; ++mt)
      af[mt] = ld16(smem + a_addr(mt * 16 + ql, t * 64 + lg * 16));
    #pragma unroll
    for (int j = 0; j < 6; ++j) {
      int n = ((j >> 1) * 16 + 2 * wid + (j & 1)) * 16 + ql;
      bf16x8 bf = ld16(smem + bb + n * 64 + ((lg * 16) ^ ((n & 3) << 4)));
      #pragma unroll
      for (int mt = 0; mt < 3; ++mt)
        acc[j * 3 + mt] = __builtin_amdgcn_mfma_f32_16x16x32_bf16(af[mt], bf, acc[j * 3 + mt], 0, 0, 0);
    }
    __syncthreads();
  }

  {
    #pragma unroll
    for (int it = 0; it < 4; ++it) {
      int g = it * 512 + tid;
      int n = g >> 3, slot = g & 7;
      const char* src = (const char*)pTq + (size_t)n * 512 + ((slot * 16) ^ ((n & 7) << 4));
      gll16(src, smem + B2_S + it * 8192 + wid * 1024);
    }
  }

  #pragma unroll
  for (int j = 0; j < 6; ++j) {
    int sec = j >> 1;
    int ncol = sec * 256 + 32 * wid + (j & 1) * 16 + ql;
    int d = (j & 1) * 16 + ql;
    float bias = qkv_b[ncol];
    float s1 = 0.f, s2 = 0.f;
    #pragma unroll
    for (int mt = 0; mt < 3; ++mt) {
      #pragma unroll
      for (int r = 0; r < 4; ++r) {
        int token = mt * 16 + lg * 4 + r;
        float v = acc[j * 3 + mt][r] + bias;
        if (token < 40) { s1 += v; s2 += v * v; }
        if (sec == 0)
          *(unsigned short*)(smem + ab + token * 80 + d * 2) = f2bf(v * SCALE_F);
        else if (sec == 1)
          *(unsigned short*)(smem + ab + AK + token * 80 + d * 2) = f2bf(v);
        else
          *(unsigned short*)(smem + ab + v_addr(d, token * 2)) = f2bf(v);
      }
    }
    s1 += __shfl_xor(s1, 16); s1 += __shfl_xor(s1, 32);
    s2 += __shfl_xor(s2, 16); s2 += __shfl_xor(s2, 32);
    if (lg == 0) { atomicAdd(ws + ncol, s1); atomicAdd(ws + 768 + ncol, s2); }
  }
  {
    int zd = lane >> 1;
    int zb = 96 + (lane & 1) * 16;
    *(int4*)(smem + ab + v_addr(zd, zb)) = (int4){0, 0, 0, 0};
  }
  asm volatile("" ::: "memory");

  f32x4 st[9];
  {
    bf16x8 kf[3], qf[3];
    #pragma unroll
    for (int a = 0; a < 3; ++a) kf[a] = ld16(smem + ab + AK + (a * 16 + ql) * 80 + lg * 16);
    #pragma unroll
    for (int b = 0; b < 3; ++b) qf[b] = ld16(smem + ab + (b * 16 + ql) * 80 + lg * 16);
    #pragma unroll
    for (int a = 0; a < 3; ++a)
      #pragma unroll
      for (int b = 0; b < 3; ++b)
        st[a * 3 + b] = __builtin_amdgcn_mfma_f32_16x16x32_bf16(
            kf[a], qf[b], (f32x4){0.f, 0.f, 0.f, 0.f}, 0, 0, 0);
  }

  float mx[3] = {-3e38f, -3e38f, -3e38f};
  #pragma unroll
  for (int a = 0; a < 3; ++a) {
    #pragma unroll
    for (int b = 0; b < 3; ++b) {
      #pragma unroll
      for (int r = 0; r < 4; ++r) {
        int kj = a * 16 + lg * 4 + r;
        int qi = b * 16 + ql;
        float s = st[a * 3 + b][r];
        if (kj < 40) {
          if (qi < 40) {
            s += bf2f(*(const unsigned short*)(smem + O_MSK + (qi * 40 + kj) * 2));
            if (kj >= 8 && qi >= 8) {
              int p = (qi - 8) * 32 + (kj - 8);
              unsigned pk = *(const unsigned*)(smem + O_IDX + ((p * 4) ^ (((p >> 5) & 7) << 4)));
              s += s_rpe[(pk & 1023) * 8 + h] + s_rpe[((pk >> 10) & 1023) * 8 + h]
                 + s_rpe[(pk >> 20) * 8 + h];
            }
          }
        } else {
          s = -1e30f;
        }
        st[a * 3 + b][r] = s;
        mx[b] = fmaxf(mx[b], s);
      }
    }
  }
  #pragma unroll
  for (int b = 0; b < 3; ++b) {
    mx[b] = fmaxf(mx[b], __shfl_xor(mx[b], 16));
    mx[b] = fmaxf(mx[b], __shfl_xor(mx[b], 32));
  }
  float sum[3] = {0.f, 0.f, 0.f};
  #pragma unroll
  for (int a = 0; a < 3; ++a)
    #pragma unroll
    for (int b = 0; b < 3; ++b)
      #pragma unroll
      for (int r = 0; r < 4; ++r) {
        float e = __expf(st[a * 3 + b][r] - mx[b]);
        st[a * 3 + b][r] = e;
        sum[b] += e;
      }
  float inv[3];
  #pragma unroll
  for (int b = 0; b < 3; ++b) {
    sum[b] += __shfl_xor(sum[b], 16);
    sum[b] += __shfl_xor(sum[b], 32);
    inv[b] = 1.f / sum[b];
  }

  f32x4 ot[6];
  #pragma unroll
  for (int i = 0; i < 6; ++i) ot[i] = (f32x4){0.f, 0.f, 0.f, 0.f};

  #pragma unroll
  for (int a = 0; a < 2; ++a)
    #pragma unroll
    for (int b = 0; b < 3; ++b)
      #pragma unroll
      for (int r = 0; r < 4; ++r) {
        int kj = a * 16 + lg * 4 + r, qi = b * 16 + ql;
        *(unsigned short*)(smem + ab + qi * 80 + kj * 2) = f2bf(st[a * 3 + b][r] * inv[b]);
      }
  asm volatile("" ::: "memory");
  {
    bf16x8 vf0 = ld16(smem + ab + v_addr(ql, lg * 16));
    bf16x8 vf1 = ld16(smem + ab + v_addr(16 + ql, lg * 16));
    #pragma unroll
    for (int b = 0; b < 3; ++b) {
      bf16x8 pf = ld16(smem + ab + (b * 16 + ql) * 80 + lg * 16);
      ot[b] = __builtin_amdgcn_mfma_f32_16x16x32_bf16(vf0, pf, ot[b], 0, 0, 0);
      ot[3 + b] = __builtin_amdgcn_mfma_f32_16x16x32_bf16(vf1, pf, ot[3 + b], 0, 0, 0);
    }
  }
  asm volatile("" ::: "memory");
  #pragma unroll
  for (int b = 0; b < 3; ++b) {
    int qi = b * 16 + ql;
    #pragma unroll
    for (int r = 0; r < 4; ++r) {
      int kj = 32 + lg * 4 + r;
      *(unsigned short*)(smem + ab + qi * 80 + (kj - 32) * 2) = f2bf(st[6 + b][r] * inv[b]);
    }
    *(uint2*)(smem + ab + qi * 80 + 32 + lg * 8) = make_uint2(0u, 0u);
  }
  asm volatile("" ::: "memory");
  {
    bf16x8 vf0 = ld16(smem + ab + v_addr(ql, 64 + lg * 16));
    bf16x8 vf1 = ld16(smem + ab + v_addr(16 + ql, 64 + lg * 16));
    #pragma unroll
    for (int b = 0; b < 3; ++b) {
      bf16x8 pf = ld16(smem + ab + (b * 16 + ql) * 80 + lg * 16);
      ot[b] = __builtin_amdgcn_mfma_f32_16x16x32_bf16(vf0, pf, ot[b], 0, 0, 0);
      ot[3 + b] = __builtin_amdgcn_mfma_f32_16x16x32_bf16(vf1, pf, ot[3 + b], 0, 0, 0);
    }
  }
  #pragma unroll
  for (int dm = 0; dm < 2; ++dm)
    #pragma unroll
    for (int b = 0; b < 3; ++b)
      #pragma unroll
      for (int r = 0; r < 4; ++r) {
        int d = dm * 16 + lg * 4 + r;
        int qi = b * 16 + ql;
        *(unsigned short*)(smem + a_addr(qi, (h * 32 + d) * 2)) = f2bf(ot[dm * 3 + b][r]);
      }
  __syncthreads();

  f32x4 oacc[6];
  #pragma unroll
  for (int i = 0; i < 6; ++i) oacc[i] = (f32x4){0.f, 0.f, 0.f, 0.f};

  for (int t = 0; t < 4; ++t) {
    if (t < 3) {
      int bb = ((t + 1) & 1) ? B2_A : B2_S;
      #pragma unroll
      for (int it = 0; it < 4; ++it) {
        int g = it * 512 + tid;
        int n = g >> 3, slot = g & 7;
        const char* src = (const char*)pTq + (size_t)n * 512 + (t + 1) * 128
                          + ((slot * 16) ^ ((n & 7) << 4));
        gll16(src, smem + bb + it * 8192 + wid * 1024);
      }
    }
    const int bb = (t & 1) ? B2_A : B2_S;
    #pragma unroll
    for (int ks = 0; ks < 2; ++ks) {
      bf16x8 af[3];
      #pragma unroll
      for (int mt = 0; mt < 3; ++mt)
        af[mt] = ld16(smem + a_addr(mt * 16 + ql, t * 128 + ks * 64 + lg * 16));
      #pragma unroll
      for (int nt = 0; nt < 2; ++nt) {
        int n = (2 * wid + nt) * 16 + ql;
        bf16x8 bf = ld16(smem + bb + n * 128 + ((ks * 64 + lg * 16) ^ ((n & 7) << 4)));
        #pragma unroll
        for (int mt = 0; mt < 3; ++mt)
          oacc[nt * 3 + mt] = __builtin_amdgcn_mfma_f32_16x16x32_bf16(af[mt], bf, oacc[nt * 3 + mt], 0, 0, 0);
      }
    }
    __syncthreads();
  }

  #pragma unroll
  for (int nt = 0; nt < 2; ++nt) {
    int ncol = (2 * wid + nt) * 16 + ql;
    float pb = proj_b[ncol];
    #pragma unroll
    for (int mt = 0; mt < 3; ++mt)
      #pragma unroll
      for (int r = 0; r < 4; ++r) {
        int token = mt * 16 + lg * 4 + r;
        if (token < 40)
          out[(size_t)w * 10240 + token * 256 + ncol] = oacc[nt * 3 + mt][r] + pb;
      }
  }
}

// =======================================================================
extern "C" void kernel_launch(void* const* d_in, const int* in_sizes, int n_in,
                              void* d_out, int out_size, void* d_ws, size_t ws_size,
                              hipStream_t stream) {
  const float* data    = (const float*)d_in[0];
  const int*   rel_pos = (const int*)d_in[1];
  const float* maskp   = (const float*)d_in[2];
  const float* qkv_w   = (const float*)d_in[3];
  const float* qkv_b   = (const float*)d_in[4];
  const float* proj_w  = (const float*)d_in[5];
  const float* proj_b  = (const float*)d_in[6];
  const float* rpe_tab = (const float*)d_in[7];
  float* out = (float*)d_out;
  float* ws  = (float*)d_ws;

  const int nw = in_sizes[1] / 3072;           // 4096
  const int total_rows = nw * 40;
  const size_t std_off = (size_t)nw * 10240;

  // ws layout (new path): [0,6144) sums | wTq 393216 | pTq 131072 | k/O 83886080
  const size_t WS_NEED = 530432ull + 83886080ull;

  unsigned short* wTq = (unsigned short*)((char*)d_ws + 6144);
  unsigned short* pTq = (unsigned short*)((char*)d_ws + 399360);

  hipMemsetAsync(ws, 0, 6144, stream);

  if (ws_size >= WS_NEED) {
    char* kg = (char*)d_ws + 530432;
    char* Og = kg;                               // O overwrites k (dead after attn reads)
    char* qg = (char*)d_out;                     // q in d_out[0, 83886080)
    char* vg = (char*)d_out + 83886080;          // v in d_out[83886080, 167772160)

    (void)hipFuncSetAttribute((const void*)octa_qkv,
                              hipFuncAttributeMaxDynamicSharedMemorySize, KQ_LDS);

    hipLaunchKernelGGL(octa_prep2, dim3(1024), dim3(256), 0, stream, qkv_w, proj_w, wTq, pTq);
    hipLaunchKernelGGL(octa_qkv, dim3(nw * 40 / 64 * 2), dim3(512), KQ_LDS, stream,
                       data, qkv_b, wTq, ws, qg, kg, vg);
    hipLaunchKernelGGL(octa_attn, dim3(nw), dim3(512), A2_LDS, stream,
                       qg, kg, vg, maskp, rel_pos, rpe_tab, Og);
    hipLaunchKernelGGL(octa_proj, dim3(nw * 40 / 128), dim3(512), P3_LDS, stream,
                       Og, pTq, proj_b, out);
    hipLaunchKernelGGL(octa_std, dim3(3), dim3(256), 0, stream, ws, out, total_rows, std_off);
  } else {
    hipLaunchKernelGGL(octa_prep_v4, dim3(1024), dim3(256), 0, stream, qkv_w, proj_w, wTq, pTq);
    (void)hipFuncSetAttribute((const void*)octa_main_v4,
                              hipFuncAttributeMaxDynamicSharedMemorySize, LDS_BYTES_V4);
    hipLaunchKernelGGL(octa_main_v4, dim3(nw), dim3(512), LDS_BYTES_V4, stream,
                       data, rel_pos, maskp, qkv_b, proj_b, rpe_tab, wTq, pTq, ws, out);
    hipLaunchKernelGGL(octa_std, dim3(3), dim3(256), 0, stream, ws, out, total_rows, std_off);
  }
}

// Round 9
// 381.154 us; speedup vs baseline: 1.3256x; 1.0470x over previous
//
#include <hip/hip_runtime.h>
#include <math.h>

// OctreeAttention: C=256, H=8, HD=32, K=32, G=8, W=40, NW=4096, RPE rows=153
#define SCALE_F 0.17677669529663687f  // 32^-0.5

typedef __bf16 bf16x8 __attribute__((ext_vector_type(8)));
typedef float f32x4 __attribute__((ext_vector_type(4)));

__device__ __forceinline__ unsigned short f2bf(float f) {
  unsigned u = __builtin_bit_cast(unsigned, f);
  u = (u + 0x7FFFu + ((u >> 16) & 1u)) >> 16;
  return (unsigned short)u;
}
__device__ __forceinline__ float bf2f(unsigned short u) {
  return __builtin_bit_cast(float, (unsigned)u << 16);
}
__device__ __forceinline__ unsigned pk2(float a, float b) {
  return (unsigned)f2bf(a) | ((unsigned)f2bf(b) << 16);
}
__device__ __forceinline__ bf16x8 ld16(const void* p) {
  int4 v = *(const int4*)p;
  return __builtin_bit_cast(bf16x8, v);
}
__device__ __forceinline__ void gll16(const void* g, void* l) {
  __builtin_amdgcn_global_load_lds(
      (const __attribute__((address_space(1))) unsigned int*)g,
      (__attribute__((address_space(3))) unsigned int*)l, 16, 0, 0);
}

// =======================================================================
// NEW PATH: 4-kernel split (needs ws_size >= 84.5 MB)
// =======================================================================

// ---- prep: weights -> bf16 ----
// wTq: chunked pre-swizzled [nc 3][kc 8][256 n][64B]; byte (n*64+cb) of chunk
// (nc,kc) holds wT[nc*256+n][kc*32 + ((cb ^ ((n>>1)&3)<<4)>>1)].
// pTq: pre-swizzled chunked layout for octa_proj's gll16 staging (unchanged).
__global__ void octa_prep2(const float* __restrict__ qkv_w, const float* __restrict__ proj_w,
                           unsigned short* __restrict__ wTq, unsigned short* __restrict__ pTq)
{
  int e = blockIdx.x * 256 + threadIdx.x;   // 262144
  if (e < 196608) {
    int c = e >> 13;                 // chunk id: nc*8 + kc
    int nc = c >> 3, kc = c & 7;
    int p2 = e & 8191;
    int n = p2 >> 5, cw = p2 & 31;
    int kl = cw ^ (((n >> 1) & 3) << 3);
    wTq[e] = f2bf(qkv_w[(size_t)(kc * 32 + kl) * 768 + nc * 256 + n]);
  } else {
    int e2 = e - 196608;
    int kc = e2 >> 13, p2 = e2 & 8191;
    int n = p2 >> 5, cw = p2 & 31;
    int kl = cw ^ (((n >> 1) & 3) << 3);
    pTq[e2] = f2bf(proj_w[(size_t)(kc * 32 + kl) * 256 + n]);
  }
}

// ---- kernel 1: qkv GEMM, m97-shaped: tile 128 rows x 256 cols, 8 waves 2Mx4N,
// wave = 64x64 (4x4 f32x4 acc, 16 MFMA : 8 ds_read per K-step). grid 1280x3
// (nc = tensor: 0=q,1=k,2=v). A reg-staged f32->bf16 dbuf; B gll16 dbuf.
#define KQ_A0 0        // 8192
#define KQ_A1 8192     // 8192
#define KQ_B0 16384    // 16384
#define KQ_B1 32768    // 16384
#define KQ_LDS 49152

__global__ __launch_bounds__(512, 4)
void octa_qkv(const float* __restrict__ data, const float* __restrict__ qkv_b,
              const unsigned short* __restrict__ wTq, float* __restrict__ ws,
              char* __restrict__ qg, char* __restrict__ kg, char* __restrict__ vg)
{
  extern __shared__ char smem[];
  const int tid = threadIdx.x, lane = tid & 63, wid = tid >> 6;
  const int ql = lane & 15, lg = lane >> 4;
  const int bm = blockIdx.x / 3, nc = blockIdx.x - bm * 3;
  const int wr = wid >> 2, wc = wid & 3;
  const char* wbase = (const char*)wTq + (size_t)nc * 131072;  // 8 chunks x 16KB

  // A staging role: thread covers 16B (8 bf16) of a 64B row quarter
  const int arow = tid >> 2, aq = tid & 3;
  const float* abase = data + ((size_t)bm * 128 + arow) * 256 + aq * 8;
  const int alds = arow * 64 + ((aq * 16) ^ (((arow >> 1) & 3) << 4));

  // prologue: A0 loads + B0 staging; write A0; sync
  float4 a0 = *(const float4*)abase;
  float4 a1 = *(const float4*)(abase + 4);
  gll16(wbase + wid * 1024 + lane * 16, smem + KQ_B0 + wid * 1024);
  gll16(wbase + 8192 + wid * 1024 + lane * 16, smem + KQ_B0 + 8192 + wid * 1024);
  *(uint2*)(smem + KQ_A0 + alds) = make_uint2(pk2(a0.x, a0.y), pk2(a0.z, a0.w));
  *(uint2*)(smem + KQ_A0 + alds + 8) = make_uint2(pk2(a1.x, a1.y), pk2(a1.z, a1.w));
  __syncthreads();

  f32x4 acc[4][4];
  #pragma unroll
  for (int m = 0; m < 4; ++m)
    #pragma unroll
    for (int n = 0; n < 4; ++n) acc[m][n] = (f32x4){0.f, 0.f, 0.f, 0.f};

  #pragma unroll
  for (int t = 0; t < 8; ++t) {
    float4 na0, na1;
    if (t < 7) {
      // issue next A (to regs) and next B (gll16) early
      na0 = *(const float4*)(abase + (t + 1) * 32);
      na1 = *(const float4*)(abase + (t + 1) * 32 + 4);
      const char* bsrc = wbase + (size_t)(t + 1) * 16384;
      char* bb1 = smem + (((t + 1) & 1) ? KQ_B1 : KQ_B0);
      gll16(bsrc + wid * 1024 + lane * 16, bb1 + wid * 1024);
      gll16(bsrc + 8192 + wid * 1024 + lane * 16, bb1 + 8192 + wid * 1024);
    }
    // compute chunk t: 8 ds_read_b128 + 16 MFMA
    const char* ab = smem + ((t & 1) ? KQ_A1 : KQ_A0);
    const char* bb = smem + ((t & 1) ? KQ_B1 : KQ_B0);
    bf16x8 af[4], bf[4];
    #pragma unroll
    for (int mt = 0; mt < 4; ++mt) {
      int row = wr * 64 + mt * 16 + ql;
      af[mt] = ld16(ab + row * 64 + ((lg * 16) ^ (((row >> 1) & 3) << 4)));
    }
    #pragma unroll
    for (int nt = 0; nt < 4; ++nt) {
      int n = wc * 64 + nt * 16 + ql;
      bf[nt] = ld16(bb + n * 64 + ((lg * 16) ^ (((n >> 1) & 3) << 4)));
    }
    #pragma unroll
    for (int nt = 0; nt < 4; ++nt)
      #pragma unroll
      for (int mt = 0; mt < 4; ++mt)
        acc[mt][nt] = __builtin_amdgcn_mfma_f32_16x16x32_bf16(af[mt], bf[nt], acc[mt][nt], 0, 0, 0);
    // write next A late (loads landed during MFMA phase)
    if (t < 7) {
      char* ab1 = smem + (((t + 1) & 1) ? KQ_A1 : KQ_A0);
      *(uint2*)(ab1 + alds) = make_uint2(pk2(na0.x, na0.y), pk2(na0.z, na0.w));
      *(uint2*)(ab1 + alds + 8) = make_uint2(pk2(na1.x, na1.y), pk2(na1.z, na1.w));
    }
    __syncthreads();
  }

  // epilogue: bias + std partials + scatter stores (one tensor per block)
  char* base = nc == 0 ? qg : (nc == 1 ? kg : vg);
  const float cs = (nc == 0) ? SCALE_F : 1.0f;
  #pragma unroll
  for (int nt = 0; nt < 4; ++nt) {
    int col = wc * 64 + nt * 16 + ql;         // [0,256)
    int h = col >> 5, d = col & 31;
    float bias = qkv_b[nc * 256 + col];
    float s1 = 0.f, s2 = 0.f;
    #pragma unroll
    for (int mt = 0; mt < 4; ++mt) {
      int tg0 = bm * 128 + wr * 64 + mt * 16 + lg * 4;  // 4-aligned, never crosses window
      int w = tg0 / 40, tk0 = tg0 - w * 40;
      size_t slice = (size_t)(w * 8 + h) * 2560;
      #pragma unroll
      for (int r = 0; r < 4; ++r) {
        float v = acc[mt][nt][r] + bias;
        s1 += v; s2 += v * v;
        *(unsigned short*)(base + slice + (tk0 + r) * 64 + d * 2) = f2bf(v * cs);
      }
    }
    s1 += __shfl_xor(s1, 16); s1 += __shfl_xor(s1, 32);
    s2 += __shfl_xor(s2, 16); s2 += __shfl_xor(s2, 32);
    if (lg == 0) {
      atomicAdd(ws + nc * 256 + col, s1);
      atomicAdd(ws + 768 + nc * 256 + col, s2);
    }
  }
}

// ---- kernel 2: attention, 1 window/block, 8 head-waves, q/k/v direct-from-global ----
// q,k,v all [w][h][tk][d]; vT fragments built by scalar gather (L2-hot slice).
#define A2_MSK 0       // mask^T bf16 [40 kj][104 B rows]
#define A2_IDX 4160    // packed idx [32 kj][128 B], XOR bit6 by kj&1
#define A2_RPT 8256    // rpeT f32 [8 h][160]
#define A2_P   13376   // per-wave P [48][80 B] x8 = 30720
#define A2_LDS 44096

__global__ __launch_bounds__(512, 4)
void octa_attn(const char* __restrict__ qg, const char* __restrict__ kg,
               const char* __restrict__ vg, const float* __restrict__ maskp,
               const int* __restrict__ rel_pos, const float* __restrict__ rpe_table,
               char* __restrict__ Og)
{
  extern __shared__ char smem[];
  const int tid = threadIdx.x, w = blockIdx.x, wid = tid >> 6;
  const int lane = tid & 63, ql = lane & 15, lg = lane >> 4, h = wid;
  const int perm = ql * 64 + lg * 16;
  const char* qb = qg + (size_t)(w * 8 + h) * 2560;
  const char* kb = kg + (size_t)(w * 8 + h) * 2560;
  const char* vb = vg + (size_t)(w * 8 + h) * 2560;

  // issue all fragment loads up-front (latency hides under phase-0 staging)
  bf16x8 kf0 = ld16(kb + perm), kf1 = ld16(kb + 1024 + perm), kf2 = ld16(kb + 2048 + perm);
  bf16x8 qf0 = ld16(qb + perm), qf1 = ld16(qb + 1024 + perm), qf2 = ld16(qb + 2048 + perm);
  // vT fragments via scalar gather: vA/vB toks 0..31, vC/vD toks 32..39
  union U8 { unsigned short u[8]; bf16x8 v; };
  U8 ua, ub, uc, ud;
  #pragma unroll
  for (int j = 0; j < 8; ++j) {
    int tok = lg * 8 + j;
    ua.u[j] = *(const unsigned short*)(vb + tok * 64 + ql * 2);
    ub.u[j] = *(const unsigned short*)(vb + tok * 64 + (16 + ql) * 2);
  }
  if (lg == 0) {
    #pragma unroll
    for (int j = 0; j < 8; ++j) {
      uc.u[j] = *(const unsigned short*)(vb + (32 + j) * 64 + ql * 2);
      ud.u[j] = *(const unsigned short*)(vb + (32 + j) * 64 + (16 + ql) * 2);
    }
  } else {
    #pragma unroll
    for (int j = 0; j < 8; ++j) { uc.u[j] = 0; ud.u[j] = 0; }
  }
  bf16x8 vA = ua.v, vB = ub.v, vC = uc.v, vD = ud.v;

  // phase 0: stage mask^T, packed idx, transposed rpe
  for (int f = tid; f < 1600; f += 512) {
    float m = maskp[(size_t)w * 1600 + f];
    int qi = f / 40, kj = f - qi * 40;
    *(unsigned short*)(smem + A2_MSK + kj * 104 + qi * 2) = f2bf(m);
  }
  for (int f = tid; f < 1024; f += 512) {
    const int* rp = rel_pos + ((size_t)w * 1024 + f) * 3;
    int c0 = rp[0], c1 = rp[1], c2 = rp[2];
    c0 = min(25, max(-25, c0)); c1 = min(25, max(-25, c1)); c2 = min(25, max(-25, c2));
    unsigned pk = (unsigned)(c0 + 25) | ((unsigned)(c1 + 76) << 10) | ((unsigned)(c2 + 127) << 20);
    int qi8 = f >> 5, kj8 = f & 31;
    *(unsigned*)(smem + A2_IDX + kj8 * 128 + ((qi8 * 4) ^ ((kj8 & 1) << 6))) = pk;
  }
  for (int f = tid; f < 1224; f += 512)
    *(float*)(smem + A2_RPT + (((f & 7) * 160 + (f >> 3)) << 2)) = rpe_table[f];
  __syncthreads();

  // QK^T: ST[kj][qi] = mfma(A=k, B=q)
  f32x4 st[9];
  {
    bf16x8 kf[3] = {kf0, kf1, kf2}, qf[3] = {qf0, qf1, qf2};
    #pragma unroll
    for (int a = 0; a < 3; ++a)
      #pragma unroll
      for (int b = 0; b < 3; ++b)
        st[a * 3 + b] = __builtin_amdgcn_mfma_f32_16x16x32_bf16(
            kf[a], qf[b], (f32x4){0.f, 0.f, 0.f, 0.f}, 0, 0, 0);
  }

  // logits + mask + rpe; per-column (qi) max
  float mx[3] = {-3e38f, -3e38f, -3e38f};
  #pragma unroll
  for (int a = 0; a < 3; ++a) {
    #pragma unroll
    for (int b = 0; b < 3; ++b) {
      #pragma unroll
      for (int r = 0; r < 4; ++r) {
        int kj = a * 16 + lg * 4 + r;
        int qi = b * 16 + ql;
        float s = st[a * 3 + b][r];
        if (kj < 40) {
          if (qi < 40) {
            s += bf2f(*(const unsigned short*)(smem + A2_MSK + kj * 104 + qi * 2));
            if (kj >= 8 && qi >= 8) {
              unsigned pk = *(const unsigned*)(smem + A2_IDX + (kj - 8) * 128 +
                                               (((qi - 8) * 4) ^ (((kj - 8) & 1) << 6)));
              s += *(const float*)(smem + A2_RPT + ((h * 160 + (pk & 1023)) << 2))
                 + *(const float*)(smem + A2_RPT + ((h * 160 + ((pk >> 10) & 1023)) << 2))
                 + *(const float*)(smem + A2_RPT + ((h * 160 + (pk >> 20)) << 2));
            }
          }
        } else {
          s = -1e30f;
        }
        st[a * 3 + b][r] = s;
        mx[b] = fmaxf(mx[b], s);
      }
    }
  }
  #pragma unroll
  for (int b = 0; b < 3; ++b) {
    mx[b] = fmaxf(mx[b], __shfl_xor(mx[b], 16));
    mx[b] = fmaxf(mx[b], __shfl_xor(mx[b], 32));
  }
  float sum[3] = {0.f, 0.f, 0.f};
  #pragma unroll
  for (int a = 0; a < 3; ++a)
    #pragma unroll
    for (int b = 0; b < 3; ++b)
      #pragma unroll
      for (int r = 0; r < 4; ++r) {
        float e = __expf(st[a * 3 + b][r] - mx[b]);
        st[a * 3 + b][r] = e;
        sum[b] += e;
      }
  float inv[3];
  #pragma unroll
  for (int b = 0; b < 3; ++b) {
    sum[b] += __shfl_xor(sum[b], 16);
    sum[b] += __shfl_xor(sum[b], 32);
    inv[b] = 1.f / sum[b];
  }

  // PV in two kj-halves; per-wave P buffer
  char* pb_ = smem + A2_P + wid * 3840;
  f32x4 ot[6];
  #pragma unroll
  for (int i = 0; i < 6; ++i) ot[i] = (f32x4){0.f, 0.f, 0.f, 0.f};

  #pragma unroll
  for (int a = 0; a < 2; ++a)
    #pragma unroll
    for (int b = 0; b < 3; ++b)
      #pragma unroll
      for (int r = 0; r < 4; ++r) {
        int kj = a * 16 + lg * 4 + r, qi = b * 16 + ql;
        *(unsigned short*)(pb_ + qi * 80 + kj * 2) = f2bf(st[a * 3 + b][r] * inv[b]);
      }
  asm volatile("" ::: "memory");
  #pragma unroll
  for (int b = 0; b < 3; ++b) {
    bf16x8 pf = ld16(pb_ + (b * 16 + ql) * 80 + lg * 16);
    ot[b]     = __builtin_amdgcn_mfma_f32_16x16x32_bf16(vA, pf, ot[b], 0, 0, 0);
    ot[3 + b] = __builtin_amdgcn_mfma_f32_16x16x32_bf16(vB, pf, ot[3 + b], 0, 0, 0);
  }
  asm volatile("" ::: "memory");
  #pragma unroll
  for (int b = 0; b < 3; ++b) {
    int qi = b * 16 + ql;
    #pragma unroll
    for (int r = 0; r < 4; ++r)
      *(unsigned short*)(pb_ + qi * 80 + (lg * 4 + r) * 2) = f2bf(st[6 + b][r] * inv[b]);
    *(uint2*)(pb_ + qi * 80 + 32 + lg * 8) = make_uint2(0u, 0u);
  }
  asm volatile("" ::: "memory");
  #pragma unroll
  for (int b = 0; b < 3; ++b) {
    bf16x8 pf = ld16(pb_ + (b * 16 + ql) * 80 + lg * 16);
    ot[b]     = __builtin_amdgcn_mfma_f32_16x16x32_bf16(vC, pf, ot[b], 0, 0, 0);
    ot[3 + b] = __builtin_amdgcn_mfma_f32_16x16x32_bf16(vD, pf, ot[3 + b], 0, 0, 0);
  }

  // O store (Og aliases kg: wait for ALL waves' k reads to be consumed)
  __syncthreads();
  #pragma unroll
  for (int dm = 0; dm < 2; ++dm)
    #pragma unroll
    for (int b = 0; b < 3; ++b) {
      int qi = b * 16 + ql;
      if (b == 2 && ql >= 8) continue;   // tokens >= 40 don't exist
      unsigned u0 = pk2(ot[dm * 3 + b][0], ot[dm * 3 + b][1]);
      unsigned u1 = pk2(ot[dm * 3 + b][2], ot[dm * 3 + b][3]);
      int tg = w * 40 + qi;
      int colb = (h * 32 + dm * 16 + lg * 4) * 2;
      *(uint2*)(Og + (size_t)tg * 512 + (colb ^ (((tg >> 1) & 3) << 4))) = make_uint2(u0, u1);
    }
}

// ---- kernel 3: proj GEMM (M=163840, N=256, K=256), all-gll16 dbuf ----
#define P3_A0 0
#define P3_A1 8192
#define P3_B0 16384
#define P3_B1 32768
#define P3_LDS 49152

__global__ __launch_bounds__(512, 4)
void octa_proj(const char* __restrict__ Og, const unsigned short* __restrict__ pTq,
               const float* __restrict__ proj_b, float* __restrict__ out)
{
  extern __shared__ char smem[];
  const int tid = threadIdx.x, lane = tid & 63, wid = tid >> 6;
  const int ql = lane & 15, lg = lane >> 4;
  const int bm = blockIdx.x;
  const int wr = wid >> 2, wc = wid & 3;
  const char* pbase = (const char*)pTq;

  // prologue: stage A0 (1 slot/thread) + B0 (2/thread)
  gll16(Og + ((size_t)bm * 128 + (tid >> 2)) * 512 + (tid & 3) * 16,
        smem + P3_A0 + wid * 1024);
  #pragma unroll
  for (int it = 0; it < 2; ++it)
    gll16(pbase + (wid * 128 + it * 64 + lane) * 16, smem + P3_B0 + wid * 2048 + it * 1024);
  __syncthreads();

  f32x4 acc[4][4];
  #pragma unroll
  for (int m = 0; m < 4; ++m)
    #pragma unroll
    for (int n = 0; n < 4; ++n) acc[m][n] = (f32x4){0.f, 0.f, 0.f, 0.f};

  #pragma unroll
  for (int t = 0; t < 8; ++t) {
    if (t < 7) {
      char* ab1 = smem + (((t + 1) & 1) ? P3_A1 : P3_A0);
      char* bb1 = smem + (((t + 1) & 1) ? P3_B1 : P3_B0);
      gll16(Og + ((size_t)bm * 128 + (tid >> 2)) * 512 + (t + 1) * 64 + (tid & 3) * 16,
            ab1 + wid * 1024);
      #pragma unroll
      for (int it = 0; it < 2; ++it)
        gll16(pbase + (size_t)(t + 1) * 16384 + (wid * 128 + it * 64 + lane) * 16,
              bb1 + wid * 2048 + it * 1024);
    }
    const char* ab = smem + ((t & 1) ? P3_A1 : P3_A0);
    const char* bb = smem + ((t & 1) ? P3_B1 : P3_B0);
    bf16x8 af[4];
    #pragma unroll
    for (int mt = 0; mt < 4; ++mt) {
      int row = wr * 64 + mt * 16 + ql;
      af[mt] = ld16(ab + row * 64 + ((lg * 16) ^ (((row >> 1) & 3) << 4)));
    }
    #pragma unroll
    for (int nt = 0; nt < 4; ++nt) {
      int n = wc * 64 + nt * 16 + ql;
      bf16x8 bf = ld16(bb + n * 64 + ((lg * 16) ^ (((n >> 1) & 3) << 4)));
      #pragma unroll
      for (int mt = 0; mt < 4; ++mt)
        acc[mt][nt] = __builtin_amdgcn_mfma_f32_16x16x32_bf16(af[mt], bf, acc[mt][nt], 0, 0, 0);
    }
    __syncthreads();
  }

  #pragma unroll
  for (int nt = 0; nt < 4; ++nt) {
    int col = wc * 64 + nt * 16 + ql;
    float pb = proj_b[col];
    #pragma unroll
    for (int mt = 0; mt < 4; ++mt)
      #pragma unroll
      for (int r = 0; r < 4; ++r) {
        int tg = bm * 128 + wr * 64 + mt * 16 + lg * 4 + r;
        out[(size_t)tg * 256 + col] = acc[mt][nt][r] + pb;
      }
  }
}

// ---- std finalize (shared by both paths) ----
__global__ void octa_std(const float* __restrict__ ws, float* __restrict__ out,
                         int total_rows, size_t off)
{
  int j = blockIdx.x * 256 + threadIdx.x;
  if (j < 768) {
    float s = ws[j], ss = ws[768 + j];
    float T = (float)total_rows;
    float var = (ss - s * s / T) / (T - 1.f);
    out[off + j] = sqrtf(fmaxf(var, 0.f));
  }
}

// =======================================================================
// FALLBACK PATH: round-4 fused kernel (verified), used if ws too small
// =======================================================================
#define O_RPE 0
#define O_MSK 4896
#define O_IDX 8096
#define O_A   12192
#define O_ATT 36768
#define B1_SZ 49152
#define ATT_STRIDE 11776
#define AK 3840
#define AV 7680
#define B2_S (O_ATT + 94208)
#define B2_A O_ATT
#define LDS_BYTES_V4 163744

__device__ __forceinline__ int a_addr(int row, int byte) {
  return O_A + row * 512 + (byte ^ ((row & 7) << 4));
}
__device__ __forceinline__ int v_addr(int d, int byte) {
  return AV + d * 128 + (byte ^ ((d & 7) << 4));
}

__global__ void octa_prep_v4(const float* __restrict__ qkv_w, const float* __restrict__ proj_w,
                             unsigned short* __restrict__ wTq, unsigned short* __restrict__ pTq)
{
  int idx = blockIdx.x * 256 + threadIdx.x;
  if (idx < 196608) {
    int n = idx >> 8, k = idx & 255;
    wTq[idx] = f2bf(qkv_w[k * 768 + n]);
  } else {
    int i = idx - 196608;
    int n = i >> 8, k = i & 255;
    pTq[i] = f2bf(proj_w[k * 256 + n]);
  }
}

__global__ __launch_bounds__(512, 2)
void octa_main_v4(const float* __restrict__ data, const int* __restrict__ rel_pos,
                  const float* __restrict__ maskp, const float* __restrict__ qkv_b,
                  const float* __restrict__ proj_b, const float* __restrict__ rpe_table,
                  const unsigned short* __restrict__ wTq, const unsigned short* __restrict__ pTq,
                  float* __restrict__ ws, float* __restrict__ out)
{
  extern __shared__ char smem[];
  float* s_rpe = (float*)(smem + O_RPE);
  const int tid = threadIdx.x;
  const int w   = blockIdx.x;
  const int wid = tid >> 6;
  const int lane = tid & 63;
  const int ql = lane & 15;
  const int lg = lane >> 4;
  const int h  = wid;
  const int ab = O_ATT + wid * ATT_STRIDE;

  {
    #pragma unroll
    for (int it = 0; it < 6; ++it) {
      int g = it * 512 + tid;
      int n = g >> 2, slot = g & 3;
      const char* src = (const char*)wTq + (size_t)n * 512 + ((slot * 16) ^ ((n & 3) << 4));
      gll16(src, smem + O_ATT + it * 8192 + wid * 1024);
    }
  }
  for (int f = tid; f < 1224; f += 512) s_rpe[f] = rpe_table[f];
  for (int f = tid; f < 400; f += 512) {
    float4 m4 = ((const float4*)(maskp + (size_t)w * 1600))[f];
    uint2 pk;
    pk.x = pk2(m4.x, m4.y); pk.y = pk2(m4.z, m4.w);
    *(uint2*)(smem + O_MSK + f * 8) = pk;
  }
  for (int p = tid; p < 1024; p += 512) {
    const int* rp = rel_pos + ((size_t)w * 1024 + p) * 3;
    int c0 = rp[0], c1 = rp[1], c2 = rp[2];
    c0 = min(25, max(-25, c0)); c1 = min(25, max(-25, c1)); c2 = min(25, max(-25, c2));
    unsigned pk = (unsigned)(c0 + 25) | ((unsigned)(c1 + 76) << 10) | ((unsigned)(c2 + 127) << 20);
    *(unsigned*)(smem + O_IDX + ((p * 4) ^ (((p >> 5) & 7) << 4))) = pk;
  }
  {
    const float4* src = (const float4*)(data + (size_t)w * 10240);
    for (int f = tid; f < 2560; f += 512) {
      int token = f >> 6, q4 = f & 63;
      float4 d4 = src[f];
      uint2 pk;
      pk.x = pk2(d4.x, d4.y); pk.y = pk2(d4.z, d4.w);
      *(uint2*)(smem + a_addr(token, q4 * 8)) = pk;
    }
    int token = 40 + (tid >> 6), byte = (tid & 63) * 8;
    *(uint2*)(smem + a_addr(token, byte)) = make_uint2(0u, 0u);
  }
  __syncthreads();

  f32x4 acc[18];
  #pragma unroll
  for (int i = 0; i < 18; ++i) acc[i] = (f32x4){0.f, 0.f, 0.f, 0.f};

  for (int t = 0; t < 8; ++t) {
    if (t < 7) {
      int bb = O_ATT + ((t + 1) & 1) * B1_SZ;
      #pragma unroll
      for (int it = 0; it < 6; ++it) {
        int g = it * 512 + tid;
        int n = g >> 2, slot = g & 3;
        const char* src = (const char*)wTq + (size_t)n * 512 + (t + 1) * 64
                          + ((slot * 16) ^ ((n & 3) << 4));
        gll16(src, smem + bb + it * 8192 + wid * 1024);
      }
    }
    const int bb = O_ATT + (t & 1) * B1_SZ;
    bf16x8 af[3];
    #pragma unroll
    for (int mt = 0; mt < 3; ++mt)
      af[mt] = ld16(smem + a_addr(mt * 16 + ql, t * 64 + lg * 16));
    #pragma unroll
    for (int j = 0; j < 6; ++j) {
      int n = ((j >> 1) * 16 + 2 * wid + (j & 1)) * 16 + ql;
      bf16x8 bf = ld16(smem + bb + n * 64 + ((lg * 16) ^ ((n & 3) << 4)));
      #pragma unroll
      for (int mt = 0; mt < 3; ++mt)
        acc[j * 3 + mt] = __builtin_amdgcn_mfma_f32_16x16x32_bf16(af[mt], bf, acc[j * 3 + mt], 0, 0, 0);
    }
    __syncthreads();
  }

  {
    #pragma unroll
    for (int it = 0; it < 4; ++it) {
      int g = it * 512 + tid;
      int n = g >> 3, slot = g & 7;
      const char* src = (const char*)pTq + (size_t)n * 512 + ((slot * 16) ^ ((n & 7) << 4));
      gll16(src, smem + B2_S + it * 8192 + wid * 1024);
    }
  }

  #pragma unroll
  for (int j = 0; j < 6; ++j) {
    int sec = j >> 1;
    int ncol = sec * 256 + 32 * wid + (j & 1) * 16 + ql;
    int d = (j & 1) * 16 + ql;
    float bias = qkv_b[ncol];
    float s1 = 0.f, s2 = 0.f;
    #pragma unroll
    for (int mt = 0; mt < 3; ++mt) {
      #pragma unroll
      for (int r = 0; r < 4; ++r) {
        int token = mt * 16 + lg * 4 + r;
        float v = acc[j * 3 + mt][r] + bias;
        if (token < 40) { s1 += v; s2 += v * v; }
        if (sec == 0)
          *(unsigned short*)(smem + ab + token * 80 + d * 2) = f2bf(v * SCALE_F);
        else if (sec == 1)
          *(unsigned short*)(smem + ab + AK + token * 80 + d * 2) = f2bf(v);
        else
          *(unsigned short*)(smem + ab + v_addr(d, token * 2)) = f2bf(v);
      }
    }
    s1 += __shfl_xor(s1, 16); s1 += __shfl_xor(s1, 32);
    s2 += __shfl_xor(s2, 16); s2 += __shfl_xor(s2, 32);
    if (lg == 0) { atomicAdd(ws + ncol, s1); atomicAdd(ws + 768 + ncol, s2); }
  }
  {
    int zd = lane >> 1;
    int zb = 96 + (lane & 1) * 16;
    *(int4*)(smem + ab + v_addr(zd, zb)) = (int4){0, 0, 0, 0};
  }
  asm volatile("" ::: "memory");

  f32x4 st[9];
  {
    bf16x8 kf[3], qf[3];
    #pragma unroll
    for (int a = 0; a < 3; ++a) kf[a] = ld16(smem + ab + AK + (a * 16 + ql) * 80 + lg * 16);
    #pragma unroll
    for (int b = 0; b < 3; ++b) qf[b] = ld16(smem + ab + (b * 16 + ql) * 80 + lg * 16);
    #pragma unroll
    for (int a = 0; a < 3; ++a)
      #pragma unroll
      for (int b = 0; b < 3; ++b)
        st[a * 3 + b] = __builtin_amdgcn_mfma_f32_16x16x32_bf16(
            kf[a], qf[b], (f32x4){0.f, 0.f, 0.f, 0.f}, 0, 0, 0);
  }

  float mx[3] = {-3e38f, -3e38f, -3e38f};
  #pragma unroll
  for (int a = 0; a < 3; ++a) {
    #pragma unroll
    for (int b = 0; b < 3; ++b) {
      #pragma unroll
      for (int r = 0; r < 4; ++r) {
        int kj = a * 16 + lg * 4 + r;
        int qi = b * 16 + ql;
        float s = st[a * 3 + b][r];
        if (kj < 40) {
          if (qi < 40) {
            s += bf2f(*(const unsigned short*)(smem + O_MSK + (qi * 40 + kj) * 2));
            if (kj >= 8 && qi >= 8) {
              int p = (qi - 8) * 32 + (kj - 8);
              unsigned pk = *(const unsigned*)(smem + O_IDX + ((p * 4) ^ (((p >> 5) & 7) << 4)));
              s += s_rpe[(pk & 1023) * 8 + h] + s_rpe[((pk >> 10) & 1023) * 8 + h]
                 + s_rpe[(pk >> 20) * 8 + h];
            }
          }
        } else {
          s = -1e30f;
        }
        st[a * 3 + b][r] = s;
        mx[b] = fmaxf(mx[b], s);
      }
    }
  }
  #pragma unroll
  for (int b = 0; b < 3; ++b) {
    mx[b] = fmaxf(mx[b], __shfl_xor(mx[b], 16));
    mx[b] = fmaxf(mx[b], __shfl_xor(mx[b], 32));
  }
  float sum[3] = {0.f, 0.f, 0.f};
  #pragma unroll
  for (int a = 0; a < 3; ++a)
    #pragma unroll
    for (int b = 0; b < 3; ++b)
      #pragma unroll
      for (int r = 0; r < 4; ++r) {
        float e = __expf(st[a * 3 + b][r] - mx[b]);
        st[a * 3 + b][r] = e;
        sum[b] += e;
      }
  float inv[3];
  #pragma unroll
  for (int b = 0; b < 3; ++b) {
    sum[b] += __shfl_xor(sum[b], 16);
    sum[b] += __shfl_xor(sum[b], 32);
    inv[b] = 1.f / sum[b];
  }

  f32x4 ot[6];
  #pragma unroll
  for (int i = 0; i < 6; ++i) ot[i] = (f32x4){0.f, 0.f, 0.f, 0.f};

  #pragma unroll
  for (int a = 0; a < 2; ++a)
    #pragma unroll
    for (int b = 0; b < 3; ++b)
      #pragma unroll
      for (int r = 0; r < 4; ++r) {
        int kj = a * 16 + lg * 4 + r, qi = b * 16 + ql;
        *(unsigned short*)(smem + ab + qi * 80 + kj * 2) = f2bf(st[a * 3 + b][r] * inv[b]);
      }
  asm volatile("" ::: "memory");
  {
    bf16x8 vf0 = ld16(smem + ab + v_addr(ql, lg * 16));
    bf16x8 vf1 = ld16(smem + ab + v_addr(16 + ql, lg * 16));
    #pragma unroll
    for (int b = 0; b < 3; ++b) {
      bf16x8 pf = ld16(smem + ab + (b * 16 + ql) * 80 + lg * 16);
      ot[b] = __builtin_amdgcn_mfma_f32_16x16x32_bf16(vf0, pf, ot[b], 0, 0, 0);
      ot[3 + b] = __builtin_amdgcn_mfma_f32_16x16x32_bf16(vf1, pf, ot[3 + b], 0, 0, 0);
    }
  }
  asm volatile("" ::: "memory");
  #pragma unroll
  for (int b = 0; b < 3; ++b) {
    int qi = b * 16 + ql;
    #pragma unroll
    for (int r = 0; r < 4; ++r) {
      int kj = 32 + lg * 4 + r;
      *(unsigned short*)(smem + ab + qi * 80 + (kj - 32) * 2) = f2bf(st[6 + b][r] * inv[b]);
    }
    *(uint2*)(smem + ab + qi * 80 + 32 + lg * 8) = make_uint2(0u, 0u);
  }
  asm volatile("" ::: "memory");
  {
    bf16x8 vf0 = ld16(smem + ab + v_addr(ql, 64 + lg * 16));
    bf16x8 vf1 = ld16(smem + ab + v_addr(16 + ql, 64 + lg * 16));
    #pragma unroll
    for (int b = 0; b < 3; ++b) {
      bf16x8 pf = ld16(smem + ab + (b * 16 + ql) * 80 + lg * 16);
      ot[b] = __builtin_amdgcn_mfma_f32_16x16x32_bf16(vf0, pf, ot[b], 0, 0, 0);
      ot[3 + b] = __builtin_amdgcn_mfma_f32_16x16x32_bf16(vf1, pf, ot[3 + b], 0, 0, 0);
    }
  }
  #pragma unroll
  for (int dm = 0; dm < 2; ++dm)
    #pragma unroll
    for (int b = 0; b < 3; ++b)
      #pragma unroll
      for (int r = 0; r < 4; ++r) {
        int d = dm * 16 + lg * 4 + r;
        int qi = b * 16 + ql;
        *(unsigned short*)(smem + a_addr(qi, (h * 32 + d) * 2)) = f2bf(ot[dm * 3 + b][r]);
      }
  __syncthreads();

  f32x4 oacc[6];
  #pragma unroll
  for (int i = 0; i < 6; ++i) oacc[i] = (f32x4){0.f, 0.f, 0.f, 0.f};

  for (int t = 0; t < 4; ++t) {
    if (t < 3) {
      int bb = ((t + 1) & 1) ? B2_A : B2_S;
      #pragma unroll
      for (int it = 0; it < 4; ++it) {
        int g = it * 512 + tid;
        int n = g >> 3, slot = g & 7;
        const char* src = (const char*)pTq + (size_t)n * 512 + (t + 1) * 128
                          + ((slot * 16) ^ ((n & 7) << 4));
        gll16(src, smem + bb + it * 8192 + wid * 1024);
      }
    }
    const int bb = (t & 1) ? B2_A : B2_S;
    #pragma unroll
    for (int ks = 0; ks < 2; ++ks) {
      bf16x8 af[3];
      #pragma unroll
      for (int mt = 0; mt < 3; ++mt)
        af[mt] = ld16(smem + a_addr(mt * 16 + ql, t * 128 + ks * 64 + lg * 16));
      #pragma unroll
      for (int nt = 0; nt < 2; ++nt) {
        int n = (2 * wid + nt) * 16 + ql;
        bf16x8 bf = ld16(smem + bb + n * 128 + ((ks * 64 + lg * 16) ^ ((n & 7) << 4)));
        #pragma unroll
        for (int mt = 0; mt < 3; ++mt)
          oacc[nt * 3 + mt] = __builtin_amdgcn_mfma_f32_16x16x32_bf16(af[mt], bf, oacc[nt * 3 + mt], 0, 0, 0);
      }
    }
    __syncthreads();
  }

  #pragma unroll
  for (int nt = 0; nt < 2; ++nt) {
    int ncol = (2 * wid + nt) * 16 + ql;
    float pb = proj_b[ncol];
    #pragma unroll
    for (int mt = 0; mt < 3; ++mt)
      #pragma unroll
      for (int r = 0; r < 4; ++r) {
        int token = mt * 16 + lg * 4 + r;
        if (token < 40)
          out[(size_t)w * 10240 + token * 256 + ncol] = oacc[nt * 3 + mt][r] + pb;
      }
  }
}

// =======================================================================
extern "C" void kernel_launch(void* const* d_in, const int* in_sizes, int n_in,
                              void* d_out, int out_size, void* d_ws, size_t ws_size,
                              hipStream_t stream) {
  const float* data    = (const float*)d_in[0];
  const int*   rel_pos = (const int*)d_in[1];
  const float* maskp   = (const float*)d_in[2];
  const float* qkv_w   = (const float*)d_in[3];
  const float* qkv_b   = (const float*)d_in[4];
  const float* proj_w  = (const float*)d_in[5];
  const float* proj_b  = (const float*)d_in[6];
  const float* rpe_tab = (const float*)d_in[7];
  float* out = (float*)d_out;
  float* ws  = (float*)d_ws;

  const int nw = in_sizes[1] / 3072;           // 4096
  const int total_rows = nw * 40;
  const size_t std_off = (size_t)nw * 10240;

  // ws layout (new path): [0,6144) sums | wTq 393216 | pTq 131072 | k/O 83886080
  const size_t WS_NEED = 530432ull + 83886080ull;

  unsigned short* wTq = (unsigned short*)((char*)d_ws + 6144);
  unsigned short* pTq = (unsigned short*)((char*)d_ws + 399360);

  hipMemsetAsync(ws, 0, 6144, stream);

  if (ws_size >= WS_NEED) {
    char* kg = (char*)d_ws + 530432;
    char* Og = kg;                               // O overwrites k (dead after attn reads)
    char* qg = (char*)d_out;                     // q in d_out[0, 83886080)
    char* vg = (char*)d_out + 83886080;          // v in d_out[83886080, 167772160)

    hipLaunchKernelGGL(octa_prep2, dim3(1024), dim3(256), 0, stream, qkv_w, proj_w, wTq, pTq);
    hipLaunchKernelGGL(octa_qkv, dim3(nw * 40 / 128 * 3), dim3(512), KQ_LDS, stream,
                       data, qkv_b, wTq, ws, qg, kg, vg);
    hipLaunchKernelGGL(octa_attn, dim3(nw), dim3(512), A2_LDS, stream,
                       qg, kg, vg, maskp, rel_pos, rpe_tab, Og);
    hipLaunchKernelGGL(octa_proj, dim3(nw * 40 / 128), dim3(512), P3_LDS, stream,
                       Og, pTq, proj_b, out);
    hipLaunchKernelGGL(octa_std, dim3(3), dim3(256), 0, stream, ws, out, total_rows, std_off);
  } else {
    hipLaunchKernelGGL(octa_prep_v4, dim3(1024), dim3(256), 0, stream, qkv_w, proj_w, wTq, pTq);
    (void)hipFuncSetAttribute((const void*)octa_main_v4,
                              hipFuncAttributeMaxDynamicSharedMemorySize, LDS_BYTES_V4);
    hipLaunchKernelGGL(octa_main_v4, dim3(nw), dim3(512), LDS_BYTES_V4, stream,
                       data, rel_pos, maskp, qkv_b, proj_b, rpe_tab, wTq, pTq, ws, out);
    hipLaunchKernelGGL(octa_std, dim3(3), dim3(256), 0, stream, ws, out, total_rows, std_off);
  }
}

// Round 10
// 365.526 us; speedup vs baseline: 1.3823x; 1.0428x over previous
//
#include <hip/hip_runtime.h>
#include <math.h>

// OctreeAttention: C=256, H=8, HD=32, K=32, G=8, W=40, NW=4096, RPE rows=153
#define SCALE_F 0.17677669529663687f  // 32^-0.5

typedef __bf16 bf16x8 __attribute__((ext_vector_type(8)));
typedef float f32x4 __attribute__((ext_vector_type(4)));

__device__ __forceinline__ unsigned short f2bf(float f) {
  unsigned u = __builtin_bit_cast(unsigned, f);
  u = (u + 0x7FFFu + ((u >> 16) & 1u)) >> 16;
  return (unsigned short)u;
}
__device__ __forceinline__ float bf2f(unsigned short u) {
  return __builtin_bit_cast(float, (unsigned)u << 16);
}
__device__ __forceinline__ unsigned pk2(float a, float b) {
  return (unsigned)f2bf(a) | ((unsigned)f2bf(b) << 16);
}
__device__ __forceinline__ bf16x8 ld16(const void* p) {
  int4 v = *(const int4*)p;
  return __builtin_bit_cast(bf16x8, v);
}
__device__ __forceinline__ void gll16(const void* g, void* l) {
  __builtin_amdgcn_global_load_lds(
      (const __attribute__((address_space(1))) unsigned int*)g,
      (__attribute__((address_space(3))) unsigned int*)l, 16, 0, 0);
}

// =======================================================================
// SPLIT/FUSED PATH kernels
// =======================================================================

// ---- prep: weights -> bf16, chunked pre-swizzled ----
__global__ void octa_prep2(const float* __restrict__ qkv_w, const float* __restrict__ proj_w,
                           unsigned short* __restrict__ wTq, unsigned short* __restrict__ pTq)
{
  int e = blockIdx.x * 256 + threadIdx.x;   // 262144
  if (e < 196608) {
    int c = e >> 13;                 // chunk id: nc*8 + kc
    int nc = c >> 3, kc = c & 7;
    int p2 = e & 8191;
    int n = p2 >> 5, cw = p2 & 31;
    int kl = cw ^ (((n >> 1) & 3) << 3);
    wTq[e] = f2bf(qkv_w[(size_t)(kc * 32 + kl) * 768 + nc * 256 + n]);
  } else {
    int e2 = e - 196608;
    int kc = e2 >> 13, p2 = e2 & 8191;
    int n = p2 >> 5, cw = p2 & 31;
    int kl = cw ^ (((n >> 1) & 3) << 3);
    pTq[e2] = f2bf(proj_w[(size_t)(kc * 32 + kl) * 256 + n]);
  }
}

// ---- kernel 1: qkv GEMM (R9-verified, unchanged) ----
#define KQ_A0 0
#define KQ_A1 8192
#define KQ_B0 16384
#define KQ_B1 32768
#define KQ_LDS 49152

__global__ __launch_bounds__(512, 4)
void octa_qkv(const float* __restrict__ data, const float* __restrict__ qkv_b,
              const unsigned short* __restrict__ wTq, float* __restrict__ ws,
              char* __restrict__ qg, char* __restrict__ kg, char* __restrict__ vg)
{
  extern __shared__ char smem[];
  const int tid = threadIdx.x, lane = tid & 63, wid = tid >> 6;
  const int ql = lane & 15, lg = lane >> 4;
  const int bm = blockIdx.x / 3, nc = blockIdx.x - bm * 3;
  const int wr = wid >> 2, wc = wid & 3;
  const char* wbase = (const char*)wTq + (size_t)nc * 131072;

  const int arow = tid >> 2, aq = tid & 3;
  const float* abase = data + ((size_t)bm * 128 + arow) * 256 + aq * 8;
  const int alds = arow * 64 + ((aq * 16) ^ (((arow >> 1) & 3) << 4));

  float4 a0 = *(const float4*)abase;
  float4 a1 = *(const float4*)(abase + 4);
  gll16(wbase + wid * 1024 + lane * 16, smem + KQ_B0 + wid * 1024);
  gll16(wbase + 8192 + wid * 1024 + lane * 16, smem + KQ_B0 + 8192 + wid * 1024);
  *(uint2*)(smem + KQ_A0 + alds) = make_uint2(pk2(a0.x, a0.y), pk2(a0.z, a0.w));
  *(uint2*)(smem + KQ_A0 + alds + 8) = make_uint2(pk2(a1.x, a1.y), pk2(a1.z, a1.w));
  __syncthreads();

  f32x4 acc[4][4];
  #pragma unroll
  for (int m = 0; m < 4; ++m)
    #pragma unroll
    for (int n = 0; n < 4; ++n) acc[m][n] = (f32x4){0.f, 0.f, 0.f, 0.f};

  #pragma unroll
  for (int t = 0; t < 8; ++t) {
    float4 na0, na1;
    if (t < 7) {
      na0 = *(const float4*)(abase + (t + 1) * 32);
      na1 = *(const float4*)(abase + (t + 1) * 32 + 4);
      const char* bsrc = wbase + (size_t)(t + 1) * 16384;
      char* bb1 = smem + (((t + 1) & 1) ? KQ_B1 : KQ_B0);
      gll16(bsrc + wid * 1024 + lane * 16, bb1 + wid * 1024);
      gll16(bsrc + 8192 + wid * 1024 + lane * 16, bb1 + 8192 + wid * 1024);
    }
    const char* ab = smem + ((t & 1) ? KQ_A1 : KQ_A0);
    const char* bb = smem + ((t & 1) ? KQ_B1 : KQ_B0);
    bf16x8 af[4], bf[4];
    #pragma unroll
    for (int mt = 0; mt < 4; ++mt) {
      int row = wr * 64 + mt * 16 + ql;
      af[mt] = ld16(ab + row * 64 + ((lg * 16) ^ (((row >> 1) & 3) << 4)));
    }
    #pragma unroll
    for (int nt = 0; nt < 4; ++nt) {
      int n = wc * 64 + nt * 16 + ql;
      bf[nt] = ld16(bb + n * 64 + ((lg * 16) ^ (((n >> 1) & 3) << 4)));
    }
    #pragma unroll
    for (int nt = 0; nt < 4; ++nt)
      #pragma unroll
      for (int mt = 0; mt < 4; ++mt)
        acc[mt][nt] = __builtin_amdgcn_mfma_f32_16x16x32_bf16(af[mt], bf[nt], acc[mt][nt], 0, 0, 0);
    if (t < 7) {
      char* ab1 = smem + (((t + 1) & 1) ? KQ_A1 : KQ_A0);
      *(uint2*)(ab1 + alds) = make_uint2(pk2(na0.x, na0.y), pk2(na0.z, na0.w));
      *(uint2*)(ab1 + alds + 8) = make_uint2(pk2(na1.x, na1.y), pk2(na1.z, na1.w));
    }
    __syncthreads();
  }

  char* base = nc == 0 ? qg : (nc == 1 ? kg : vg);
  const float cs = (nc == 0) ? SCALE_F : 1.0f;
  #pragma unroll
  for (int nt = 0; nt < 4; ++nt) {
    int col = wc * 64 + nt * 16 + ql;
    int h = col >> 5, d = col & 31;
    float bias = qkv_b[nc * 256 + col];
    float s1 = 0.f, s2 = 0.f;
    #pragma unroll
    for (int mt = 0; mt < 4; ++mt) {
      int tg0 = bm * 128 + wr * 64 + mt * 16 + lg * 4;
      int w = tg0 / 40, tk0 = tg0 - w * 40;
      size_t slice = (size_t)(w * 8 + h) * 2560;
      #pragma unroll
      for (int r = 0; r < 4; ++r) {
        float v = acc[mt][nt][r] + bias;
        s1 += v; s2 += v * v;
        *(unsigned short*)(base + slice + (tk0 + r) * 64 + d * 2) = f2bf(v * cs);
      }
    }
    s1 += __shfl_xor(s1, 16); s1 += __shfl_xor(s1, 32);
    s2 += __shfl_xor(s2, 16); s2 += __shfl_xor(s2, 32);
    if (lg == 0) {
      atomicAdd(ws + nc * 256 + col, s1);
      atomicAdd(ws + 768 + nc * 256 + col, s2);
    }
  }
}

// ================= FUSED attention+proj (tier-1) =================
// LDS: attn phase 44096 (msk/idx/rpt/P); proj phase aliases:
//   s_o [48][512B] swz @0 (24576), B dbuf @24576/@40960 (2x16384) -> 57344
#define F_MSK 0
#define F_IDX 4160
#define F_RPT 8256
#define F_P   13376
#define F_O   0
#define F_B0  24576
#define F_B1  40960
#define F_LDS 57344

__global__ __launch_bounds__(512, 4)
void octa_attnproj(const char* __restrict__ qg, const char* __restrict__ kg,
                   const char* __restrict__ vg, const float* __restrict__ maskp,
                   const int* __restrict__ rel_pos, const float* __restrict__ rpe_table,
                   const unsigned short* __restrict__ pTq, const float* __restrict__ proj_b,
                   float* __restrict__ out)
{
  extern __shared__ char smem[];
  const int tid = threadIdx.x, w = blockIdx.x, wid = tid >> 6;
  const int lane = tid & 63, ql = lane & 15, lg = lane >> 4, h = wid;
  const int perm = ql * 64 + lg * 16;
  const char* qb = qg + (size_t)(w * 8 + h) * 2560;
  const char* kb = kg + (size_t)(w * 8 + h) * 2560;
  const char* vb = vg + (size_t)(w * 8 + h) * 2560;

  bf16x8 kf0 = ld16(kb + perm), kf1 = ld16(kb + 1024 + perm), kf2 = ld16(kb + 2048 + perm);
  bf16x8 qf0 = ld16(qb + perm), qf1 = ld16(qb + 1024 + perm), qf2 = ld16(qb + 2048 + perm);
  union U8 { unsigned short u[8]; bf16x8 v; };
  U8 ua, ub, uc, ud;
  #pragma unroll
  for (int j = 0; j < 8; ++j) {
    int tok = lg * 8 + j;
    ua.u[j] = *(const unsigned short*)(vb + tok * 64 + ql * 2);
    ub.u[j] = *(const unsigned short*)(vb + tok * 64 + (16 + ql) * 2);
  }
  if (lg == 0) {
    #pragma unroll
    for (int j = 0; j < 8; ++j) {
      uc.u[j] = *(const unsigned short*)(vb + (32 + j) * 64 + ql * 2);
      ud.u[j] = *(const unsigned short*)(vb + (32 + j) * 64 + (16 + ql) * 2);
    }
  } else {
    #pragma unroll
    for (int j = 0; j < 8; ++j) { uc.u[j] = 0; ud.u[j] = 0; }
  }
  bf16x8 vA = ua.v, vB = ub.v, vC = uc.v, vD = ud.v;

  for (int f = tid; f < 1600; f += 512) {
    float m = maskp[(size_t)w * 1600 + f];
    int qi = f / 40, kj = f - qi * 40;
    *(unsigned short*)(smem + F_MSK + kj * 104 + qi * 2) = f2bf(m);
  }
  for (int f = tid; f < 1024; f += 512) {
    const int* rp = rel_pos + ((size_t)w * 1024 + f) * 3;
    int c0 = rp[0], c1 = rp[1], c2 = rp[2];
    c0 = min(25, max(-25, c0)); c1 = min(25, max(-25, c1)); c2 = min(25, max(-25, c2));
    unsigned pk = (unsigned)(c0 + 25) | ((unsigned)(c1 + 76) << 10) | ((unsigned)(c2 + 127) << 20);
    int qi8 = f >> 5, kj8 = f & 31;
    *(unsigned*)(smem + F_IDX + kj8 * 128 + ((qi8 * 4) ^ ((kj8 & 1) << 6))) = pk;
  }
  for (int f = tid; f < 1224; f += 512)
    *(float*)(smem + F_RPT + (((f & 7) * 160 + (f >> 3)) << 2)) = rpe_table[f];
  __syncthreads();

  f32x4 st[9];
  {
    bf16x8 kf[3] = {kf0, kf1, kf2}, qf[3] = {qf0, qf1, qf2};
    __builtin_amdgcn_s_setprio(1);
    #pragma unroll
    for (int a = 0; a < 3; ++a)
      #pragma unroll
      for (int b = 0; b < 3; ++b)
        st[a * 3 + b] = __builtin_amdgcn_mfma_f32_16x16x32_bf16(
            kf[a], qf[b], (f32x4){0.f, 0.f, 0.f, 0.f}, 0, 0, 0);
    __builtin_amdgcn_s_setprio(0);
  }

  float mx[3] = {-3e38f, -3e38f, -3e38f};
  #pragma unroll
  for (int a = 0; a < 3; ++a) {
    #pragma unroll
    for (int b = 0; b < 3; ++b) {
      #pragma unroll
      for (int r = 0; r < 4; ++r) {
        int kj = a * 16 + lg * 4 + r;
        int qi = b * 16 + ql;
        float s = st[a * 3 + b][r];
        if (kj < 40) {
          if (qi < 40) {
            s += bf2f(*(const unsigned short*)(smem + F_MSK + kj * 104 + qi * 2));
            if (kj >= 8 && qi >= 8) {
              unsigned pk = *(const unsigned*)(smem + F_IDX + (kj - 8) * 128 +
                                               (((qi - 8) * 4) ^ (((kj - 8) & 1) << 6)));
              s += *(const float*)(smem + F_RPT + ((h * 160 + (pk & 1023)) << 2))
                 + *(const float*)(smem + F_RPT + ((h * 160 + ((pk >> 10) & 1023)) << 2))
                 + *(const float*)(smem + F_RPT + ((h * 160 + (pk >> 20)) << 2));
            }
          }
        } else {
          s = -1e30f;
        }
        st[a * 3 + b][r] = s;
        mx[b] = fmaxf(mx[b], s);
      }
    }
  }
  #pragma unroll
  for (int b = 0; b < 3; ++b) {
    mx[b] = fmaxf(mx[b], __shfl_xor(mx[b], 16));
    mx[b] = fmaxf(mx[b], __shfl_xor(mx[b], 32));
  }
  float sum[3] = {0.f, 0.f, 0.f};
  #pragma unroll
  for (int a = 0; a < 3; ++a)
    #pragma unroll
    for (int b = 0; b < 3; ++b)
      #pragma unroll
      for (int r = 0; r < 4; ++r) {
        float e = __expf(st[a * 3 + b][r] - mx[b]);
        st[a * 3 + b][r] = e;
        sum[b] += e;
      }
  float inv[3];
  #pragma unroll
  for (int b = 0; b < 3; ++b) {
    sum[b] += __shfl_xor(sum[b], 16);
    sum[b] += __shfl_xor(sum[b], 32);
    inv[b] = 1.f / sum[b];
  }

  char* pb_ = smem + F_P + wid * 3840;
  f32x4 ot[6];
  #pragma unroll
  for (int i = 0; i < 6; ++i) ot[i] = (f32x4){0.f, 0.f, 0.f, 0.f};

  #pragma unroll
  for (int a = 0; a < 2; ++a)
    #pragma unroll
    for (int b = 0; b < 3; ++b)
      #pragma unroll
      for (int r = 0; r < 4; ++r) {
        int kj = a * 16 + lg * 4 + r, qi = b * 16 + ql;
        *(unsigned short*)(pb_ + qi * 80 + kj * 2) = f2bf(st[a * 3 + b][r] * inv[b]);
      }
  asm volatile("" ::: "memory");
  __builtin_amdgcn_s_setprio(1);
  #pragma unroll
  for (int b = 0; b < 3; ++b) {
    bf16x8 pf = ld16(pb_ + (b * 16 + ql) * 80 + lg * 16);
    ot[b]     = __builtin_amdgcn_mfma_f32_16x16x32_bf16(vA, pf, ot[b], 0, 0, 0);
    ot[3 + b] = __builtin_amdgcn_mfma_f32_16x16x32_bf16(vB, pf, ot[3 + b], 0, 0, 0);
  }
  __builtin_amdgcn_s_setprio(0);
  asm volatile("" ::: "memory");
  #pragma unroll
  for (int b = 0; b < 3; ++b) {
    int qi = b * 16 + ql;
    #pragma unroll
    for (int r = 0; r < 4; ++r)
      *(unsigned short*)(pb_ + qi * 80 + (lg * 4 + r) * 2) = f2bf(st[6 + b][r] * inv[b]);
    *(uint2*)(pb_ + qi * 80 + 32 + lg * 8) = make_uint2(0u, 0u);
  }
  asm volatile("" ::: "memory");
  __builtin_amdgcn_s_setprio(1);
  #pragma unroll
  for (int b = 0; b < 3; ++b) {
    bf16x8 pf = ld16(pb_ + (b * 16 + ql) * 80 + lg * 16);
    ot[b]     = __builtin_amdgcn_mfma_f32_16x16x32_bf16(vC, pf, ot[b], 0, 0, 0);
    ot[3 + b] = __builtin_amdgcn_mfma_f32_16x16x32_bf16(vD, pf, ot[3 + b], 0, 0, 0);
  }
  __builtin_amdgcn_s_setprio(0);

  // ---- phase switch: all waves done with msk/idx/rpt/P ----
  __syncthreads();
  // stage proj-B chunk0 + write O to s_o[qi][h*32+d] (swz)
  #pragma unroll
  for (int it = 0; it < 2; ++it)
    gll16((const char*)pTq + (wid * 128 + it * 64 + lane) * 16,
          smem + F_B0 + wid * 2048 + it * 1024);
  #pragma unroll
  for (int dm = 0; dm < 2; ++dm)
    #pragma unroll
    for (int b = 0; b < 3; ++b) {
      int qi = b * 16 + ql;
      unsigned u0 = pk2(ot[dm * 3 + b][0], ot[dm * 3 + b][1]);
      unsigned u1 = pk2(ot[dm * 3 + b][2], ot[dm * 3 + b][3]);
      int colb = (h * 32 + dm * 16 + lg * 4) * 2;
      *(uint2*)(smem + F_O + qi * 512 + (colb ^ ((qi & 7) << 4))) = make_uint2(u0, u1);
    }
  __syncthreads();   // s_o visible; B0 staged (vmcnt drained)

  // ---- proj: out[40x256] = s_o[40x256] @ proj_w, wave = 48 rows x 32 cols ----
  f32x4 pacc[3][2];
  #pragma unroll
  for (int m = 0; m < 3; ++m)
    #pragma unroll
    for (int n = 0; n < 2; ++n) pacc[m][n] = (f32x4){0.f, 0.f, 0.f, 0.f};
  const int c0 = wid * 32;

  #pragma unroll
  for (int t = 0; t < 8; ++t) {
    if (t < 7) {
      char* bb1 = smem + (((t + 1) & 1) ? F_B1 : F_B0);
      #pragma unroll
      for (int it = 0; it < 2; ++it)
        gll16((const char*)pTq + (size_t)(t + 1) * 16384 + (wid * 128 + it * 64 + lane) * 16,
              bb1 + wid * 2048 + it * 1024);
    }
    const char* bb = smem + ((t & 1) ? F_B1 : F_B0);
    bf16x8 af[3], bfr[2];
    #pragma unroll
    for (int mt = 0; mt < 3; ++mt) {
      int row = mt * 16 + ql;
      af[mt] = ld16(smem + F_O + row * 512 + ((t * 64 + lg * 16) ^ ((row & 7) << 4)));
    }
    #pragma unroll
    for (int nt = 0; nt < 2; ++nt) {
      int n = c0 + nt * 16 + ql;
      bfr[nt] = ld16(bb + n * 64 + ((lg * 16) ^ (((n >> 1) & 3) << 4)));
    }
    __builtin_amdgcn_s_setprio(1);
    #pragma unroll
    for (int nt = 0; nt < 2; ++nt)
      #pragma unroll
      for (int mt = 0; mt < 3; ++mt)
        pacc[mt][nt] = __builtin_amdgcn_mfma_f32_16x16x32_bf16(af[mt], bfr[nt], pacc[mt][nt], 0, 0, 0);
    __builtin_amdgcn_s_setprio(0);
    __syncthreads();
  }

  #pragma unroll
  for (int nt = 0; nt < 2; ++nt) {
    int col = c0 + nt * 16 + ql;
    float pb = proj_b[col];
    #pragma unroll
    for (int mt = 0; mt < 3; ++mt)
      #pragma unroll
      for (int r = 0; r < 4; ++r) {
        int row = mt * 16 + lg * 4 + r;
        if (row < 40)
          out[(size_t)(w * 40 + row) * 256 + col] = pacc[mt][nt][r] + pb;
      }
  }
}

// ---- kernel 2 (tier-2): attention only, writes Og ----
#define A2_MSK 0
#define A2_IDX 4160
#define A2_RPT 8256
#define A2_P   13376
#define A2_LDS 44096

__global__ __launch_bounds__(512, 4)
void octa_attn(const char* __restrict__ qg, const char* __restrict__ kg,
               const char* __restrict__ vg, const float* __restrict__ maskp,
               const int* __restrict__ rel_pos, const float* __restrict__ rpe_table,
               char* __restrict__ Og)
{
  extern __shared__ char smem[];
  const int tid = threadIdx.x, w = blockIdx.x, wid = tid >> 6;
  const int lane = tid & 63, ql = lane & 15, lg = lane >> 4, h = wid;
  const int perm = ql * 64 + lg * 16;
  const char* qb = qg + (size_t)(w * 8 + h) * 2560;
  const char* kb = kg + (size_t)(w * 8 + h) * 2560;
  const char* vb = vg + (size_t)(w * 8 + h) * 2560;

  bf16x8 kf0 = ld16(kb + perm), kf1 = ld16(kb + 1024 + perm), kf2 = ld16(kb + 2048 + perm);
  bf16x8 qf0 = ld16(qb + perm), qf1 = ld16(qb + 1024 + perm), qf2 = ld16(qb + 2048 + perm);
  union U8 { unsigned short u[8]; bf16x8 v; };
  U8 ua, ub, uc, ud;
  #pragma unroll
  for (int j = 0; j < 8; ++j) {
    int tok = lg * 8 + j;
    ua.u[j] = *(const unsigned short*)(vb + tok * 64 + ql * 2);
    ub.u[j] = *(const unsigned short*)(vb + tok * 64 + (16 + ql) * 2);
  }
  if (lg == 0) {
    #pragma unroll
    for (int j = 0; j < 8; ++j) {
      uc.u[j] = *(const unsigned short*)(vb + (32 + j) * 64 + ql * 2);
      ud.u[j] = *(const unsigned short*)(vb + (32 + j) * 64 + (16 + ql) * 2);
    }
  } else {
    #pragma unroll
    for (int j = 0; j < 8; ++j) { uc.u[j] = 0; ud.u[j] = 0; }
  }
  bf16x8 vA = ua.v, vB = ub.v, vC = uc.v, vD = ud.v;

  for (int f = tid; f < 1600; f += 512) {
    float m = maskp[(size_t)w * 1600 + f];
    int qi = f / 40, kj = f - qi * 40;
    *(unsigned short*)(smem + A2_MSK + kj * 104 + qi * 2) = f2bf(m);
  }
  for (int f = tid; f < 1024; f += 512) {
    const int* rp = rel_pos + ((size_t)w * 1024 + f) * 3;
    int c0 = rp[0], c1 = rp[1], c2 = rp[2];
    c0 = min(25, max(-25, c0)); c1 = min(25, max(-25, c1)); c2 = min(25, max(-25, c2));
    unsigned pk = (unsigned)(c0 + 25) | ((unsigned)(c1 + 76) << 10) | ((unsigned)(c2 + 127) << 20);
    int qi8 = f >> 5, kj8 = f & 31;
    *(unsigned*)(smem + A2_IDX + kj8 * 128 + ((qi8 * 4) ^ ((kj8 & 1) << 6))) = pk;
  }
  for (int f = tid; f < 1224; f += 512)
    *(float*)(smem + A2_RPT + (((f & 7) * 160 + (f >> 3)) << 2)) = rpe_table[f];
  __syncthreads();

  f32x4 st[9];
  {
    bf16x8 kf[3] = {kf0, kf1, kf2}, qf[3] = {qf0, qf1, qf2};
    __builtin_amdgcn_s_setprio(1);
    #pragma unroll
    for (int a = 0; a < 3; ++a)
      #pragma unroll
      for (int b = 0; b < 3; ++b)
        st[a * 3 + b] = __builtin_amdgcn_mfma_f32_16x16x32_bf16(
            kf[a], qf[b], (f32x4){0.f, 0.f, 0.f, 0.f}, 0, 0, 0);
    __builtin_amdgcn_s_setprio(0);
  }

  float mx[3] = {-3e38f, -3e38f, -3e38f};
  #pragma unroll
  for (int a = 0; a < 3; ++a) {
    #pragma unroll
    for (int b = 0; b < 3; ++b) {
      #pragma unroll
      for (int r = 0; r < 4; ++r) {
        int kj = a * 16 + lg * 4 + r;
        int qi = b * 16 + ql;
        float s = st[a * 3 + b][r];
        if (kj < 40) {
          if (qi < 40) {
            s += bf2f(*(const unsigned short*)(smem + A2_MSK + kj * 104 + qi * 2));
            if (kj >= 8 && qi >= 8) {
              unsigned pk = *(const unsigned*)(smem + A2_IDX + (kj - 8) * 128 +
                                               (((qi - 8) * 4) ^ (((kj - 8) & 1) << 6)));
              s += *(const float*)(smem + A2_RPT + ((h * 160 + (pk & 1023)) << 2))
                 + *(const float*)(smem + A2_RPT + ((h * 160 + ((pk >> 10) & 1023)) << 2))
                 + *(const float*)(smem + A2_RPT + ((h * 160 + (pk >> 20)) << 2));
            }
          }
        } else {
          s = -1e30f;
        }
        st[a * 3 + b][r] = s;
        mx[b] = fmaxf(mx[b], s);
      }
    }
  }
  #pragma unroll
  for (int b = 0; b < 3; ++b) {
    mx[b] = fmaxf(mx[b], __shfl_xor(mx[b], 16));
    mx[b] = fmaxf(mx[b], __shfl_xor(mx[b], 32));
  }
  float sum[3] = {0.f, 0.f, 0.f};
  #pragma unroll
  for (int a = 0; a < 3; ++a)
    #pragma unroll
    for (int b = 0; b < 3; ++b)
      #pragma unroll
      for (int r = 0; r < 4; ++r) {
        float e = __expf(st[a * 3 + b][r] - mx[b]);
        st[a * 3 + b][r] = e;
        sum[b] += e;
      }
  float inv[3];
  #pragma unroll
  for (int b = 0; b < 3; ++b) {
    sum[b] += __shfl_xor(sum[b], 16);
    sum[b] += __shfl_xor(sum[b], 32);
    inv[b] = 1.f / sum[b];
  }

  char* pb_ = smem + A2_P + wid * 3840;
  f32x4 ot[6];
  #pragma unroll
  for (int i = 0; i < 6; ++i) ot[i] = (f32x4){0.f, 0.f, 0.f, 0.f};

  #pragma unroll
  for (int a = 0; a < 2; ++a)
    #pragma unroll
    for (int b = 0; b < 3; ++b)
      #pragma unroll
      for (int r = 0; r < 4; ++r) {
        int kj = a * 16 + lg * 4 + r, qi = b * 16 + ql;
        *(unsigned short*)(pb_ + qi * 80 + kj * 2) = f2bf(st[a * 3 + b][r] * inv[b]);
      }
  asm volatile("" ::: "memory");
  __builtin_amdgcn_s_setprio(1);
  #pragma unroll
  for (int b = 0; b < 3; ++b) {
    bf16x8 pf = ld16(pb_ + (b * 16 + ql) * 80 + lg * 16);
    ot[b]     = __builtin_amdgcn_mfma_f32_16x16x32_bf16(vA, pf, ot[b], 0, 0, 0);
    ot[3 + b] = __builtin_amdgcn_mfma_f32_16x16x32_bf16(vB, pf, ot[3 + b], 0, 0, 0);
  }
  __builtin_amdgcn_s_setprio(0);
  asm volatile("" ::: "memory");
  #pragma unroll
  for (int b = 0; b < 3; ++b) {
    int qi = b * 16 + ql;
    #pragma unroll
    for (int r = 0; r < 4; ++r)
      *(unsigned short*)(pb_ + qi * 80 + (lg * 4 + r) * 2) = f2bf(st[6 + b][r] * inv[b]);
    *(uint2*)(pb_ + qi * 80 + 32 + lg * 8) = make_uint2(0u, 0u);
  }
  asm volatile("" ::: "memory");
  __builtin_amdgcn_s_setprio(1);
  #pragma unroll
  for (int b = 0; b < 3; ++b) {
    bf16x8 pf = ld16(pb_ + (b * 16 + ql) * 80 + lg * 16);
    ot[b]     = __builtin_amdgcn_mfma_f32_16x16x32_bf16(vC, pf, ot[b], 0, 0, 0);
    ot[3 + b] = __builtin_amdgcn_mfma_f32_16x16x32_bf16(vD, pf, ot[3 + b], 0, 0, 0);
  }
  __builtin_amdgcn_s_setprio(0);

  __syncthreads();
  #pragma unroll
  for (int dm = 0; dm < 2; ++dm)
    #pragma unroll
    for (int b = 0; b < 3; ++b) {
      int qi = b * 16 + ql;
      if (b == 2 && ql >= 8) continue;
      unsigned u0 = pk2(ot[dm * 3 + b][0], ot[dm * 3 + b][1]);
      unsigned u1 = pk2(ot[dm * 3 + b][2], ot[dm * 3 + b][3]);
      int tg = w * 40 + qi;
      int colb = (h * 32 + dm * 16 + lg * 4) * 2;
      *(uint2*)(Og + (size_t)tg * 512 + (colb ^ (((tg >> 1) & 3) << 4))) = make_uint2(u0, u1);
    }
}

// ---- kernel 3 (tier-2): proj GEMM ----
#define P3_A0 0
#define P3_A1 8192
#define P3_B0 16384
#define P3_B1 32768
#define P3_LDS 49152

__global__ __launch_bounds__(512, 4)
void octa_proj(const char* __restrict__ Og, const unsigned short* __restrict__ pTq,
               const float* __restrict__ proj_b, float* __restrict__ out)
{
  extern __shared__ char smem[];
  const int tid = threadIdx.x, lane = tid & 63, wid = tid >> 6;
  const int ql = lane & 15, lg = lane >> 4;
  const int bm = blockIdx.x;
  const int wr = wid >> 2, wc = wid & 3;
  const char* pbase = (const char*)pTq;

  gll16(Og + ((size_t)bm * 128 + (tid >> 2)) * 512 + (tid & 3) * 16,
        smem + P3_A0 + wid * 1024);
  #pragma unroll
  for (int it = 0; it < 2; ++it)
    gll16(pbase + (wid * 128 + it * 64 + lane) * 16, smem + P3_B0 + wid * 2048 + it * 1024);
  __syncthreads();

  f32x4 acc[4][4];
  #pragma unroll
  for (int m = 0; m < 4; ++m)
    #pragma unroll
    for (int n = 0; n < 4; ++n) acc[m][n] = (f32x4){0.f, 0.f, 0.f, 0.f};

  #pragma unroll
  for (int t = 0; t < 8; ++t) {
    if (t < 7) {
      char* ab1 = smem + (((t + 1) & 1) ? P3_A1 : P3_A0);
      char* bb1 = smem + (((t + 1) & 1) ? P3_B1 : P3_B0);
      gll16(Og + ((size_t)bm * 128 + (tid >> 2)) * 512 + (t + 1) * 64 + (tid & 3) * 16,
            ab1 + wid * 1024);
      #pragma unroll
      for (int it = 0; it < 2; ++it)
        gll16(pbase + (size_t)(t + 1) * 16384 + (wid * 128 + it * 64 + lane) * 16,
              bb1 + wid * 2048 + it * 1024);
    }
    const char* ab = smem + ((t & 1) ? P3_A1 : P3_A0);
    const char* bb = smem + ((t & 1) ? P3_B1 : P3_B0);
    bf16x8 af[4];
    #pragma unroll
    for (int mt = 0; mt < 4; ++mt) {
      int row = wr * 64 + mt * 16 + ql;
      af[mt] = ld16(ab + row * 64 + ((lg * 16) ^ (((row >> 1) & 3) << 4)));
    }
    #pragma unroll
    for (int nt = 0; nt < 4; ++nt) {
      int n = wc * 64 + nt * 16 + ql;
      bf16x8 bf = ld16(bb + n * 64 + ((lg * 16) ^ (((n >> 1) & 3) << 4)));
      #pragma unroll
      for (int mt = 0; mt < 4; ++mt)
        acc[mt][nt] = __builtin_amdgcn_mfma_f32_16x16x32_bf16(af[mt], bf, acc[mt][nt], 0, 0, 0);
    }
    __syncthreads();
  }

  #pragma unroll
  for (int nt = 0; nt < 4; ++nt) {
    int col = wc * 64 + nt * 16 + ql;
    float pb = proj_b[col];
    #pragma unroll
    for (int mt = 0; mt < 4; ++mt)
      #pragma unroll
      for (int r = 0; r < 4; ++r) {
        int tg = bm * 128 + wr * 64 + mt * 16 + lg * 4 + r;
        out[(size_t)tg * 256 + col] = acc[mt][nt][r] + pb;
      }
  }
}

// ---- std finalize (all paths) ----
__global__ void octa_std(const float* __restrict__ ws, float* __restrict__ out,
                         int total_rows, size_t off)
{
  int j = blockIdx.x * 256 + threadIdx.x;
  if (j < 768) {
    float s = ws[j], ss = ws[768 + j];
    float T = (float)total_rows;
    float var = (ss - s * s / T) / (T - 1.f);
    out[off + j] = sqrtf(fmaxf(var, 0.f));
  }
}

// =======================================================================
// FALLBACK PATH: round-4 fused kernel (verified), used if ws too small
// =======================================================================
#define O_RPE 0
#define O_MSK 4896
#define O_IDX 8096
#define O_A   12192
#define O_ATT 36768
#define B1_SZ 49152
#define ATT_STRIDE 11776
#define AK 3840
#define AV 7680
#define B2_S (O_ATT + 94208)
#define B2_A O_ATT
#define LDS_BYTES_V4 163744

__device__ __forceinline__ int a_addr(int row, int byte) {
  return O_A + row * 512 + (byte ^ ((row & 7) << 4));
}
__device__ __forceinline__ int v_addr(int d, int byte) {
  return AV + d * 128 + (byte ^ ((d & 7) << 4));
}

__global__ void octa_prep_v4(const float* __restrict__ qkv_w, const float* __restrict__ proj_w,
                             unsigned short* __restrict__ wTq, unsigned short* __restrict__ pTq)
{
  int idx = blockIdx.x * 256 + threadIdx.x;
  if (idx < 196608) {
    int n = idx >> 8, k = idx & 255;
    wTq[idx] = f2bf(qkv_w[k * 768 + n]);
  } else {
    int i = idx - 196608;
    int n = i >> 8, k = i & 255;
    pTq[i] = f2bf(proj_w[k * 256 + n]);
  }
}

__global__ __launch_bounds__(512, 2)
void octa_main_v4(const float* __restrict__ data, const int* __restrict__ rel_pos,
                  const float* __restrict__ maskp, const float* __restrict__ qkv_b,
                  const float* __restrict__ proj_b, const float* __restrict__ rpe_table,
                  const unsigned short* __restrict__ wTq, const unsigned short* __restrict__ pTq,
                  float* __restrict__ ws, float* __restrict__ out)
{
  extern __shared__ char smem[];
  float* s_rpe = (float*)(smem + O_RPE);
  const int tid = threadIdx.x;
  const int w   = blockIdx.x;
  const int wid = tid >> 6;
  const int lane = tid & 63;
  const int ql = lane & 15;
  const int lg = lane >> 4;
  const int h  = wid;
  const int ab = O_ATT + wid * ATT_STRIDE;

  {
    #pragma unroll
    for (int it = 0; it < 6; ++it) {
      int g = it * 512 + tid;
      int n = g >> 2, slot = g & 3;
      const char* src = (const char*)wTq + (size_t)n * 512 + ((slot * 16) ^ ((n & 3) << 4));
      gll16(src, smem + O_ATT + it * 8192 + wid * 1024);
    }
  }
  for (int f = tid; f < 1224; f += 512) s_rpe[f] = rpe_table[f];
  for (int f = tid; f < 400; f += 512) {
    float4 m4 = ((const float4*)(maskp + (size_t)w * 1600))[f];
    uint2 pk;
    pk.x = pk2(m4.x, m4.y); pk.y = pk2(m4.z, m4.w);
    *(uint2*)(smem + O_MSK + f * 8) = pk;
  }
  for (int p = tid; p < 1024; p += 512) {
    const int* rp = rel_pos + ((size_t)w * 1024 + p) * 3;
    int c0 = rp[0], c1 = rp[1], c2 = rp[2];
    c0 = min(25, max(-25, c0)); c1 = min(25, max(-25, c1)); c2 = min(25, max(-25, c2));
    unsigned pk = (unsigned)(c0 + 25) | ((unsigned)(c1 + 76) << 10) | ((unsigned)(c2 + 127) << 20);
    *(unsigned*)(smem + O_IDX + ((p * 4) ^ (((p >> 5) & 7) << 4))) = pk;
  }
  {
    const float4* src = (const float4*)(data + (size_t)w * 10240);
    for (int f = tid; f < 2560; f += 512) {
      int token = f >> 6, q4 = f & 63;
      float4 d4 = src[f];
      uint2 pk;
      pk.x = pk2(d4.x, d4.y); pk.y = pk2(d4.z, d4.w);
      *(uint2*)(smem + a_addr(token, q4 * 8)) = pk;
    }
    int token = 40 + (tid >> 6), byte = (tid & 63) * 8;
    *(uint2*)(smem + a_addr(token, byte)) = make_uint2(0u, 0u);
  }
  __syncthreads();

  f32x4 acc[18];
  #pragma unroll
  for (int i = 0; i < 18; ++i) acc[i] = (f32x4){0.f, 0.f, 0.f, 0.f};

  for (int t = 0; t < 8; ++t) {
    if (t < 7) {
      int bb = O_ATT + ((t + 1) & 1) * B1_SZ;
      #pragma unroll
      for (int it = 0; it < 6; ++it) {
        int g = it * 512 + tid;
        int n = g >> 2, slot = g & 3;
        const char* src = (const char*)wTq + (size_t)n * 512 + (t + 1) * 64
                          + ((slot * 16) ^ ((n & 3) << 4));
        gll16(src, smem + bb + it * 8192 + wid * 1024);
      }
    }
    const int bb = O_ATT + (t & 1) * B1_SZ;
    bf16x8 af[3];
    #pragma unroll
    for (int mt = 0; mt < 3; ++mt)
      af[mt] = ld16(smem + a_addr(mt * 16 + ql, t * 64 + lg * 16));
    #pragma unroll
    for (int j = 0; j < 6; ++j) {
      int n = ((j >> 1) * 16 + 2 * wid + (j & 1)) * 16 + ql;
      bf16x8 bf = ld16(smem + bb + n * 64 + ((lg * 16) ^ ((n & 3) << 4)));
      #pragma unroll
      for (int mt = 0; mt < 3; ++mt)
        acc[j * 3 + mt] = __builtin_amdgcn_mfma_f32_16x16x32_bf16(af[mt], bf, acc[j * 3 + mt], 0, 0, 0);
    }
    __syncthreads();
  }

  {
    #pragma unroll
    for (int it = 0; it < 4; ++it) {
      int g = it * 512 + tid;
      int n = g >> 3, slot = g & 7;
      const char* src = (const char*)pTq + (size_t)n * 512 + ((slot * 16) ^ ((n & 7) << 4));
      gll16(src, smem + B2_S + it * 8192 + wid * 1024);
    }
  }

  #pragma unroll
  for (int j = 0; j < 6; ++j) {
    int sec = j >> 1;
    int ncol = sec * 256 + 32 * wid + (j & 1) * 16 + ql;
    int d = (j & 1) * 16 + ql;
    float bias = qkv_b[ncol];
    float s1 = 0.f, s2 = 0.f;
    #pragma unroll
    for (int mt = 0; mt < 3; ++mt) {
      #pragma unroll
      for (int r = 0; r < 4; ++r) {
        int token = mt * 16 + lg * 4 + r;
        float v = acc[j * 3 + mt][r] + bias;
        if (token < 40) { s1 += v; s2 += v * v; }
        if (sec == 0)
          *(unsigned short*)(smem + ab + token * 80 + d * 2) = f2bf(v * SCALE_F);
        else if (sec == 1)
          *(unsigned short*)(smem + ab + AK + token * 80 + d * 2) = f2bf(v);
        else
          *(unsigned short*)(smem + ab + v_addr(d, token * 2)) = f2bf(v);
      }
    }
    s1 += __shfl_xor(s1, 16); s1 += __shfl_xor(s1, 32);
    s2 += __shfl_xor(s2, 16); s2 += __shfl_xor(s2, 32);
    if (lg == 0) { atomicAdd(ws + ncol, s1); atomicAdd(ws + 768 + ncol, s2); }
  }
  {
    int zd = lane >> 1;
    int zb = 96 + (lane & 1) * 16;
    *(int4*)(smem + ab + v_addr(zd, zb)) = (int4){0, 0, 0, 0};
  }
  asm volatile("" ::: "memory");

  f32x4 st[9];
  {
    bf16x8 kf[3], qf[3];
    #pragma unroll
    for (int a = 0; a < 3; ++a) kf[a] = ld16(smem + ab + AK + (a * 16 + ql) * 80 + lg * 16);
    #pragma unroll
    for (int b = 0; b < 3; ++b) qf[b] = ld16(smem + ab + (b * 16 + ql) * 80 + lg * 16);
    #pragma unroll
    for (int a = 0; a < 3; ++a)
      #pragma unroll
      for (int b = 0; b < 3; ++b)
        st[a * 3 + b] = __builtin_amdgcn_mfma_f32_16x16x32_bf16(
            kf[a], qf[b], (f32x4){0.f, 0.f, 0.f, 0.f}, 0, 0, 0);
  }

  float mx[3] = {-3e38f, -3e38f, -3e38f};
  #pragma unroll
  for (int a = 0; a < 3; ++a) {
    #pragma unroll
    for (int b = 0; b < 3; ++b) {
      #pragma unroll
      for (int r = 0; r < 4; ++r) {
        int kj = a * 16 + lg * 4 + r;
        int qi = b * 16 + ql;
        float s = st[a * 3 + b][r];
        if (kj < 40) {
          if (qi < 40) {
            s += bf2f(*(const unsigned short*)(smem + O_MSK + (qi * 40 + kj) * 2));
            if (kj >= 8 && qi >= 8) {
              int p = (qi - 8) * 32 + (kj - 8);
              unsigned pk = *(const unsigned*)(smem + O_IDX + ((p * 4) ^ (((p >> 5) & 7) << 4)));
              s += s_rpe[(pk & 1023) * 8 + h] + s_rpe[((pk >> 10) & 1023) * 8 + h]
                 + s_rpe[(pk >> 20) * 8 + h];
            }
          }
        } else {
          s = -1e30f;
        }
        st[a * 3 + b][r] = s;
        mx[b] = fmaxf(mx[b], s);
      }
    }
  }
  #pragma unroll
  for (int b = 0; b < 3; ++b) {
    mx[b] = fmaxf(mx[b], __shfl_xor(mx[b], 16));
    mx[b] = fmaxf(mx[b], __shfl_xor(mx[b], 32));
  }
  float sum[3] = {0.f, 0.f, 0.f};
  #pragma unroll
  for (int a = 0; a < 3; ++a)
    #pragma unroll
    for (int b = 0; b < 3; ++b)
      #pragma unroll
      for (int r = 0; r < 4; ++r) {
        float e = __expf(st[a * 3 + b][r] - mx[b]);
        st[a * 3 + b][r] = e;
        sum[b] += e;
      }
  float inv[3];
  #pragma unroll
  for (int b = 0; b < 3; ++b) {
    sum[b] += __shfl_xor(sum[b], 16);
    sum[b] += __shfl_xor(sum[b], 32);
    inv[b] = 1.f / sum[b];
  }

  f32x4 ot[6];
  #pragma unroll
  for (int i = 0; i < 6; ++i) ot[i] = (f32x4){0.f, 0.f, 0.f, 0.f};

  #pragma unroll
  for (int a = 0; a < 2; ++a)
    #pragma unroll
    for (int b = 0; b < 3; ++b)
      #pragma unroll
      for (int r = 0; r < 4; ++r) {
        int kj = a * 16 + lg * 4 + r, qi = b * 16 + ql;
        *(unsigned short*)(smem + ab + qi * 80 + kj * 2) = f2bf(st[a * 3 + b][r] * inv[b]);
      }
  asm volatile("" ::: "memory");
  {
    bf16x8 vf0 = ld16(smem + ab + v_addr(ql, lg * 16));
    bf16x8 vf1 = ld16(smem + ab + v_addr(16 + ql, lg * 16));
    #pragma unroll
    for (int b = 0; b < 3; ++b) {
      bf16x8 pf = ld16(smem + ab + (b * 16 + ql) * 80 + lg * 16);
      ot[b] = __builtin_amdgcn_mfma_f32_16x16x32_bf16(vf0, pf, ot[b], 0, 0, 0);
      ot[3 + b] = __builtin_amdgcn_mfma_f32_16x16x32_bf16(vf1, pf, ot[3 + b], 0, 0, 0);
    }
  }
  asm volatile("" ::: "memory");
  #pragma unroll
  for (int b = 0; b < 3; ++b) {
    int qi = b * 16 + ql;
    #pragma unroll
    for (int r = 0; r < 4; ++r) {
      int kj = 32 + lg * 4 + r;
      *(unsigned short*)(smem + ab + qi * 80 + (kj - 32) * 2) = f2bf(st[6 + b][r] * inv[b]);
    }
    *(uint2*)(smem + ab + qi * 80 + 32 + lg * 8) = make_uint2(0u, 0u);
  }
  asm volatile("" ::: "memory");
  {
    bf16x8 vf0 = ld16(smem + ab + v_addr(ql, 64 + lg * 16));
    bf16x8 vf1 = ld16(smem + ab + v_addr(16 + ql, 64 + lg * 16));
    #pragma unroll
    for (int b = 0; b < 3; ++b) {
      bf16x8 pf = ld16(smem + ab + (b * 16 + ql) * 80 + lg * 16);
      ot[b] = __builtin_amdgcn_mfma_f32_16x16x32_bf16(vf0, pf, ot[b], 0, 0, 0);
      ot[3 + b] = __builtin_amdgcn_mfma_f32_16x16x32_bf16(vf1, pf, ot[3 + b], 0, 0, 0);
    }
  }
  #pragma unroll
  for (int dm = 0; dm < 2; ++dm)
    #pragma unroll
    for (int b = 0; b < 3; ++b)
      #pragma unroll
      for (int r = 0; r < 4; ++r) {
        int d = dm * 16 + lg * 4 + r;
        int qi = b * 16 + ql;
        *(unsigned short*)(smem + a_addr(qi, (h * 32 + d) * 2)) = f2bf(ot[dm * 3 + b][r]);
      }
  __syncthreads();

  f32x4 oacc[6];
  #pragma unroll
  for (int i = 0; i < 6; ++i) oacc[i] = (f32x4){0.f, 0.f, 0.f, 0.f};

  for (int t = 0; t < 4; ++t) {
    if (t < 3) {
      int bb = ((t + 1) & 1) ? B2_A : B2_S;
      #pragma unroll
      for (int it = 0; it < 4; ++it) {
        int g = it * 512 + tid;
        int n = g >> 3, slot = g & 7;
        const char* src = (const char*)pTq + (size_t)n * 512 + (t + 1) * 128
                          + ((slot * 16) ^ ((n & 7) << 4));
        gll16(src, smem + bb + it * 8192 + wid * 1024);
      }
    }
    const int bb = (t & 1) ? B2_A : B2_S;
    #pragma unroll
    for (int ks = 0; ks < 2; ++ks) {
      bf16x8 af[3];
      #pragma unroll
      for (int mt = 0; mt < 3; ++mt)
        af[mt] = ld16(smem + a_addr(mt * 16 + ql, t * 128 + ks * 64 + lg * 16));
      #pragma unroll
      for (int nt = 0; nt < 2; ++nt) {
        int n = (2 * wid + nt) * 16 + ql;
        bf16x8 bf = ld16(smem + bb + n * 128 + ((ks * 64 + lg * 16) ^ ((n & 7) << 4)));
        #pragma unroll
        for (int mt = 0; mt < 3; ++mt)
          oacc[nt * 3 + mt] = __builtin_amdgcn_mfma_f32_16x16x32_bf16(af[mt], bf, oacc[nt * 3 + mt], 0, 0, 0);
      }
    }
    __syncthreads();
  }

  #pragma unroll
  for (int nt = 0; nt < 2; ++nt) {
    int ncol = (2 * wid + nt) * 16 + ql;
    float pb = proj_b[ncol];
    #pragma unroll
    for (int mt = 0; mt < 3; ++mt)
      #pragma unroll
      for (int r = 0; r < 4; ++r) {
        int token = mt * 16 + lg * 4 + r;
        if (token < 40)
          out[(size_t)w * 10240 + token * 256 + ncol] = oacc[nt * 3 + mt][r] + pb;
      }
  }
}

// =======================================================================
extern "C" void kernel_launch(void* const* d_in, const int* in_sizes, int n_in,
                              void* d_out, int out_size, void* d_ws, size_t ws_size,
                              hipStream_t stream) {
  const float* data    = (const float*)d_in[0];
  const int*   rel_pos = (const int*)d_in[1];
  const float* maskp   = (const float*)d_in[2];
  const float* qkv_w   = (const float*)d_in[3];
  const float* qkv_b   = (const float*)d_in[4];
  const float* proj_w  = (const float*)d_in[5];
  const float* proj_b  = (const float*)d_in[6];
  const float* rpe_tab = (const float*)d_in[7];
  float* out = (float*)d_out;
  float* ws  = (float*)d_ws;

  const int nw = in_sizes[1] / 3072;           // 4096
  const int total_rows = nw * 40;
  const size_t std_off = (size_t)nw * 10240;
  const size_t SZ = 83886080ull;               // one q/k/v tensor, bf16

  // tier-1 (fused attn+proj): q,k,v all in ws   | tier-2: q,v in d_out, k in ws
  const size_t WS1 = 530432ull + 3ull * SZ + 4096ull;
  const size_t WS2 = 530432ull + SZ;

  unsigned short* wTq = (unsigned short*)((char*)d_ws + 6144);
  unsigned short* pTq = (unsigned short*)((char*)d_ws + 399360);

  hipMemsetAsync(ws, 0, 6144, stream);

  if (ws_size >= WS1) {
    char* qg = (char*)d_ws + 530432;
    char* kg = qg + SZ;
    char* vg = kg + SZ;
    (void)hipFuncSetAttribute((const void*)octa_attnproj,
                              hipFuncAttributeMaxDynamicSharedMemorySize, F_LDS);
    hipLaunchKernelGGL(octa_prep2, dim3(1024), dim3(256), 0, stream, qkv_w, proj_w, wTq, pTq);
    hipLaunchKernelGGL(octa_qkv, dim3(nw * 40 / 128 * 3), dim3(512), KQ_LDS, stream,
                       data, qkv_b, wTq, ws, qg, kg, vg);
    hipLaunchKernelGGL(octa_attnproj, dim3(nw), dim3(512), F_LDS, stream,
                       qg, kg, vg, maskp, rel_pos, rpe_tab, pTq, proj_b, out);
    hipLaunchKernelGGL(octa_std, dim3(3), dim3(256), 0, stream, ws, out, total_rows, std_off);
  } else if (ws_size >= WS2) {
    char* kg = (char*)d_ws + 530432;
    char* Og = kg;                               // O overwrites k (dead after attn reads)
    char* qg = (char*)d_out;                     // q in d_out[0, SZ)
    char* vg = (char*)d_out + SZ;                // v in d_out[SZ, 2*SZ)

    hipLaunchKernelGGL(octa_prep2, dim3(1024), dim3(256), 0, stream, qkv_w, proj_w, wTq, pTq);
    hipLaunchKernelGGL(octa_qkv, dim3(nw * 40 / 128 * 3), dim3(512), KQ_LDS, stream,
                       data, qkv_b, wTq, ws, qg, kg, vg);
    hipLaunchKernelGGL(octa_attn, dim3(nw), dim3(512), A2_LDS, stream,
                       qg, kg, vg, maskp, rel_pos, rpe_tab, Og);
    hipLaunchKernelGGL(octa_proj, dim3(nw * 40 / 128), dim3(512), P3_LDS, stream,
                       Og, pTq, proj_b, out);
    hipLaunchKernelGGL(octa_std, dim3(3), dim3(256), 0, stream, ws, out, total_rows, std_off);
  } else {
    hipLaunchKernelGGL(octa_prep_v4, dim3(1024), dim3(256), 0, stream, qkv_w, proj_w, wTq, pTq);
    (void)hipFuncSetAttribute((const void*)octa_main_v4,
                              hipFuncAttributeMaxDynamicSharedMemorySize, LDS_BYTES_V4);
    hipLaunchKernelGGL(octa_main_v4, dim3(nw), dim3(512), LDS_BYTES_V4, stream,
                       data, rel_pos, maskp, qkv_b, proj_b, rpe_tab, wTq, pTq, ws, out);
    hipLaunchKernelGGL(octa_std, dim3(3), dim3(256), 0, stream, ws, out, total_rows, std_off);
  }
}